// Round 3
// baseline (768.337 us; speedup 1.0000x reference)
//
#include <hip/hip_runtime.h>
#include <hip/hip_bf16.h>
#include <math.h>

#define BB 256
#define NN 184
#define HH 128
#define FF 8
#define TH 24
#define TF 24
#define KA 160       // augmented K (128 h + x block + pad; k=139 = bias col)
#define NG 512       // 4 gate-parts x 128
#define RPAD 192     // padded row count (12 tiles of 16)
#define STRH 136     // Ah row stride (elems)
#define NT 1024      // 16 waves, 4/SIMD
#define NW3 552      // mask words per (b,t)
#define EMAX 4096    // LDS edge cache capacity (expected nE ~3386)
#define LOG2E 1.44269504088896f

// per-(b,t) staging record, 16B-granular, layout mirrored in LDS:
//   fore: [mask 552*8 = 4416][dinv 184*4 = 736][G 184*4 = 736][AxF 184*16 = 2944] = 8832
//   hist: [AxF 2944]  (loaded at LDS offset OFF_AXF)
#define REC_F 8832
#define REC_H 2944
#define OFF_DINV 4416
#define OFF_G 5152
#define OFF_AXF 5888

typedef __attribute__((ext_vector_type(8))) short bf16x8;
typedef __attribute__((ext_vector_type(4))) short bf16x4;
typedef __attribute__((ext_vector_type(4))) float f32x4;
typedef __attribute__((ext_vector_type(2))) unsigned u32x2;

#if __has_builtin(__builtin_amdgcn_mfma_f32_16x16x16bf16_1k)
#define XK16 1
#else
#define XK16 0
#endif

__host__ __device__ __forceinline__ long recOff(int b, int t) {
    const long PB = (long)TH * REC_H + (long)TF * REC_F;
    return (long)b * PB + ((t < TH) ? (long)t * REC_H
                                    : (long)TH * REC_H + (long)(t - TH) * REC_F);
}

__device__ __forceinline__ unsigned short f2bf(float f) {
    unsigned u = __float_as_uint(f);
    u += 0x7fffu + ((u >> 16) & 1u);
    return (unsigned short)(u >> 16);
}
__device__ __forceinline__ unsigned pkbf(float a, float b) {
    __hip_bfloat162 h = __float22bfloat162_rn(make_float2(a, b));
    return *reinterpret_cast<unsigned*>(&h);
}
__device__ __forceinline__ void gload16(const void* src, void* dst) {
    __builtin_amdgcn_global_load_lds(
        (const __attribute__((address_space(1))) unsigned int*)src,
        (__attribute__((address_space(3))) unsigned int*)dst, 16, 0, 0);
}

// ---------------------------------------------------------------------------
// Augmented bf16 weights Wa[512][160] (R, Z, NH, NX), PRESCALED:
//   R,Z rows (incl. bias col 139) * log2e      -> sigmoid = rcp(1+exp2(-a))
//   NH,NX rows (incl. bias cols)  * 2*log2e    -> tanh via exp2(-|w|)
// X-block slots (k-128): 0..7 = features (hist: slot0 = p), 8 = xn, 9 = g,
// 11 = bias (pairs with const-1 in AxR[3]). All x-slots fit in K=16.
// ---------------------------------------------------------------------------
__global__ void prep_weights(const float* __restrict__ WhhH, const float* __restrict__ WihH,
                             const float* __restrict__ WhhF, const float* __restrict__ WihF,
                             const float* __restrict__ bihH, const float* __restrict__ bhhH,
                             const float* __restrict__ bihF, const float* __restrict__ bhhF,
                             unsigned short* __restrict__ WaH, unsigned short* __restrict__ WaF) {
    int idx = blockIdx.x * 256 + threadIdx.x;
    if (idx >= NG * KA) return;
    int jp = idx / KA, k = idx % KA;
    int j = jp & 127, part = jp >> 7;
    float vh = 0.f, vf = 0.f;
    if (part <= 1) {              // R, Z
        int row = part * 128 + j;
        if (k < 128) { vh = WhhH[row * 128 + k]; vf = WhhF[row * 128 + k]; }
        else {
            int s = k - 128;
            if (s == 0)  vh = WihH[row * 2 + 1];
            if (s < 8)   vf = WihF[row * 10 + (s + 1)];
            if (s == 8)  { vh = WihH[row * 2 + 0]; vf = WihF[row * 10 + 0]; }
            if (s == 9)  vf = WihF[row * 10 + 9];
            if (s == 11) { vh = bihH[row] + bhhH[row]; vf = bihF[row] + bhhF[row]; }
        }
    } else if (part == 2) {       // NH: h part of n-gate + bhh at bias col
        if (k < 128) { vh = WhhH[(256 + j) * 128 + k]; vf = WhhF[(256 + j) * 128 + k]; }
        else if (k == 139) { vh = bhhH[256 + j]; vf = bhhF[256 + j]; }
    } else {                      // NX: x part of n-gate | bih@139
        if (k >= 128) {
            int s = k - 128;
            if (s == 0)  vh = WihH[(256 + j) * 2 + 1];
            if (s < 8)   vf = WihF[(256 + j) * 10 + (s + 1)];
            if (s == 8)  { vh = WihH[(256 + j) * 2 + 0]; vf = WihF[(256 + j) * 10 + 0]; }
            if (s == 9)  vf = WihF[(256 + j) * 10 + 9];
            if (s == 11) { vh = bihH[256 + j]; vf = bihF[256 + j]; }
        }
    }
    float sc = (part <= 1) ? LOG2E : 2.0f * LOG2E;
    WaH[idx] = f2bf(vh * sc);
    WaF[idx] = f2bf(vf * sc);
}

// ---------------------------------------------------------------------------
// Sparse edge list over adj: rec = (c1, c2, i, j) as float4.
// ---------------------------------------------------------------------------
__global__ void prep_edges(const float* __restrict__ angles, const float* __restrict__ adj,
                           float4* __restrict__ edges, int* __restrict__ cnt) {
    int idx = blockIdx.x * 256 + threadIdx.x;
    if (idx < NN * NN && adj[idx] > 0.f) {
        float a = angles[idx];
        int pos = atomicAdd(cnt, 1);
        float4 r;
        r.x = cosf(a);
        r.y = cosf(a - 1.57079632679489662f);
        r.z = __int_as_float(idx / NN);   // i (source)
        r.w = __int_as_float(idx % NN);   // j (dest)
        edges[pos] = r;
    }
}

// ---------------------------------------------------------------------------
// Record builder: ONE block per batch, edges cached in LDS once, t-loop
// inside (kills the 650 MB of per-(b,t) edge re-reads).
// Hist records: AxF = {p,0,...} bf16 rows. Fore records: bitmask, dinv,
// G (feature-channel cheb contribution + bias), AxF bf16 features.
// ---------------------------------------------------------------------------
__global__ __launch_bounds__(256) void prep_graph(
    const float* __restrict__ feature, const float* __restrict__ pm25,
    const float4* __restrict__ edges, const int* __restrict__ ecnt,
    const float* __restrict__ cw0, const float* __restrict__ cw1,
    const float* __restrict__ cbb, char* __restrict__ xrec)
{
    const int b = blockIdx.x;
    const int tid = threadIdx.x;
    __shared__ float4 eL[EMAX];                  // 64 KB edge cache
    __shared__ float f8[NN * FF];
    __shared__ unsigned long long mT[NN][3];
    __shared__ int dg[NN];
    __shared__ float di[NN];

    // hist records: bf16 {p,0,...} rows
    for (int it = tid; it < TH * NN; it += 256) {
        int tt = it / NN, j = it - tt * NN;
        unsigned short pb = f2bf(pm25[((long)b * TH + tt) * NN + j]);
        uint4* dst = (uint4*)(xrec + recOff(b, tt)) + j;
        *dst = make_uint4((unsigned)pb, 0u, 0u, 0u);
    }

    const int nEfull = *ecnt;
    const int nEL = (nEfull < EMAX) ? nEfull : EMAX;
    for (int e = tid; e < nEL; e += 256) eL[e] = edges[e];

    float w0c[8], w1c[8];
    #pragma unroll
    for (int c = 0; c < 8; ++c) { w0c[c] = cw0[c + 1]; w1c[c] = cw1[c + 1]; }
    const float cb = cbb[0];

    for (int tt = TH; tt < TH + TF; ++tt) {
        char* rec = xrec + recOff(b, tt);
        const float4* fb4 = (const float4*)(feature + ((long)b * (TH + TF) + tt) * (NN * FF));
        __syncthreads();   // eL ready (first iter) / prev gather done (mT reuse)
        for (int i = tid; i < (NN * FF) / 4; i += 256) ((float4*)f8)[i] = fb4[i];
        for (int i = tid; i < NN * 3; i += 256) ((unsigned long long*)mT)[i] = 0ull;
        for (int i = tid; i < NN; i += 256) dg[i] = 0;
        __syncthreads();
        for (int e = tid; e < nEfull; e += 256) {
            float4 r = (e < nEL) ? eL[e] : edges[e];
            int ii = __float_as_int(r.z), jj = __float_as_int(r.w);
            if (f8[ii * FF] * r.x + f8[ii * FF + 1] * r.y >= 0.5f) {
                atomicAdd(&dg[ii], 1);
                atomicOr(&mT[jj][ii >> 6], 1ull << (ii & 63));
            }
        }
        __syncthreads();
        if (tid < NN) di[tid] = (dg[tid] > 0) ? rsqrtf((float)dg[tid]) : 0.f;
        __syncthreads();
        unsigned long long* mr = (unsigned long long*)rec;
        for (int i = tid; i < NW3; i += 256) mr[i] = ((const unsigned long long*)mT)[i];
        if (tid < NN) {
            int j = tid;
            float acc[8];
            #pragma unroll
            for (int c = 0; c < 8; ++c) acc[c] = 0.f;
            #pragma unroll
            for (int wd = 0; wd < 3; ++wd) {
                unsigned long long m = mT[j][wd];
                while (m) {
                    int bp = __ffsll(m) - 1; m &= m - 1;
                    int i = wd * 64 + bp;
                    float d = di[i];
                    #pragma unroll
                    for (int c = 0; c < 8; ++c) acc[c] += d * f8[i * FF + c];
                }
            }
            float dj = di[j];
            float hzj = (dj > 0.f) ? 0.f : -1.f;
            float G = cb;
            #pragma unroll
            for (int c = 0; c < 8; ++c) {
                float xv = f8[j * FF + c];
                float y = -dj * acc[c] + hzj * xv;
                G += xv * w0c[c] + y * w1c[c];
            }
            ((float*)(rec + OFF_DINV))[j] = dj;
            ((float*)(rec + OFF_G))[j] = G;
            unsigned short* ax = (unsigned short*)(rec + OFF_AXF) + j * 8;
            #pragma unroll
            for (int c = 0; c < 8; ++c) ax[c] = f2bf(f8[j * FF + c]);
        }
    }
}

// ---------------------------------------------------------------------------
// Persistent fused kernel: one block per batch, 1024 threads (16 waves,
// 4/SIMD, 128-VGPR cap). Register diet to fit: h kept as packed bf16 pairs
// (hpk, 12 regs) and x-block MFMA at K=16 (wregX 8 regs) -> ~112 peak, no
// spills. Per fore step: [cheb gather+finalize | bar] [stage(t+1) async +
// GEMM + epilogue + fc partials | bar] [xn reduce | bar].
// ---------------------------------------------------------------------------
__global__ __launch_bounds__(NT, 4) void fused_dgc(
    const unsigned short* __restrict__ WaH,
    const unsigned short* __restrict__ WaF,
    const float* __restrict__ fchw, const float* __restrict__ fchb,
    const float* __restrict__ fcow, const float* __restrict__ fcob,
    const float* __restrict__ cw0, const float* __restrict__ cw1,
    const char* __restrict__ xrec,
    float* __restrict__ pred)
{
    __shared__ unsigned short Ah[2][RPAD * STRH];   // 104,448 B
    __shared__ unsigned short AxR[RPAD * 8];        //   3,072 B (xn, g, -, 1.0, 0..)
    __shared__ __align__(16) char stg[2][8960];     //  17,920 B
    __shared__ float red_s[RPAD * 9];               //   6,912 B (fc partials)
    __shared__ float2 dx_s[NN];                     //   1,472 B (.x = dinv, .y = xn)
    __shared__ float fcls_f[132];                   //     528 B (fc w fp32 + bias@128)
    __shared__ unsigned short zero16[8];            //      16 B

    const int tid = threadIdx.x;
    const int bb = blockIdx.x;
    const int w = tid >> 6, lane = tid & 63, q = lane >> 4, lq = lane & 15;
    const int cg = w & 7, rh = w >> 3;

    for (int i = tid; i < RPAD * STRH; i += NT) Ah[0][i] = 0;
    for (int i = tid; i < RPAD * 8; i += NT)
        AxR[i] = ((i & 7) == 3) ? (unsigned short)0x3F80 : (unsigned short)0;
    if (tid < 8) zero16[tid] = 0;
    if (tid < NN) dx_s[tid] = make_float2(0.f, 0.f);

    // ---- phase weights in registers ----
    bf16x8 wregH[3][4];   // g = R,Z,NH : kc 0..3 (h part)
#if XK16
    bf16x4 wregX[4];      // g = R,Z,NH,NX : x block, K=16
#else
    bf16x8 wregX[4];      // K=32 fallback
#endif
    auto load_phase = [&](const unsigned short* Wa, const float* fcw, const float* fcb) {
        const int jcol = cg * 16 + lq;
        #pragma unroll
        for (int g = 0; g < 3; ++g)
            #pragma unroll
            for (int kc = 0; kc < 4; ++kc)
                wregH[g][kc] = *(const bf16x8*)(Wa + (long)(g * 128 + jcol) * KA + kc * 32 + q * 8);
        #pragma unroll
        for (int g = 0; g < 4; ++g)
#if XK16
            wregX[g] = *(const bf16x4*)(Wa + (long)(g * 128 + jcol) * KA + 128 + q * 4);
#else
            wregX[g] = *(const bf16x8*)(Wa + (long)(g * 128 + jcol) * KA + 128 + q * 8);
#endif
        if (tid < 132) fcls_f[tid] = (tid < 128) ? fcw[tid] : ((tid == 128) ? fcb[0] : 0.f);
    };
    load_phase(WaH, fchw, fchb);

    // ---- stage t=0 record ----
    if (tid < NN)
        gload16(xrec + recOff(bb, 0) + (long)tid * 16,
                (char*)stg[0] + OFF_AXF + (tid & ~63) * 16);

    const float w00 = cw0[0], w10 = cw1[0];

    unsigned hpk[12];      // h as packed bf16 pairs: rows rh*96+rl*16+lq, cols 16cg+4q+{0..3}
    #pragma unroll
    for (int i = 0; i < 12; ++i) hpk[i] = 0u;

    int p = 0;
    __syncthreads();       // init + stage(0) visible

    for (int t = 0; t < TH + TF; ++t) {
        const unsigned long long* maskS = (const unsigned long long*)stg[p];
        const float* GS = (const float*)(stg[p] + OFF_G);
        const unsigned short* AxFS = (const unsigned short*)(stg[p] + OFF_AXF);

        // ============ cheb gate (fore): gather + finalize in ONE phase =====
        if (t >= TH) {
            const int jg = tid >> 2, wd = tid & 3;
            if (jg < NN) {
                unsigned long long m = (wd < 3) ? maskS[jg * 3 + wd] : 0ull;
                float acc = 0.f;
                while (m) {
                    int bp = __ffsll(m) - 1; m &= m - 1;
                    float2 dxv = dx_s[wd * 64 + bp];
                    acc += dxv.x * dxv.y;
                }
                acc += __shfl_xor(acc, 1);
                acc += __shfl_xor(acc, 2);
                if (wd == 0) {
                    float2 dxj = dx_s[jg];
                    float hzj = (dxj.x > 0.f) ? 0.f : -1.f;
                    float y0 = -dxj.x * acc + hzj * dxj.y;
                    float pre = GS[jg] + dxj.y * w00 + y0 * w10;
                    float g = __builtin_amdgcn_rcpf(1.0f + exp2f(-LOG2E * pre));
                    AxR[jg * 8 + 1] = f2bf(g);
                }
            }
            __syncthreads();
        }

        // ====== issue t+1 staging (async global->LDS, lands by next bar) ===
        const int t2 = t + 1;
        if (t2 < TH + TF) {
            const int nch = (t2 < TH) ? NN : NW3;
            if (tid < nch)
                gload16(xrec + recOff(bb, t2) + (long)tid * 16,
                        (char*)stg[p ^ 1] + ((t2 < TH) ? OFF_AXF : 0) + (tid & ~63) * 16);
        }

        // ========== GRU GEMM + epilogue + fc partials (6 row-tiles) ========
        f32x4 fw = *(const f32x4*)&fcls_f[cg * 16 + q * 4];
        #pragma unroll
        for (int rl = 0; rl < 6; ++rl) {
            const int row = rh * 96 + rl * 16 + lq;
            const int ro = row * STRH;
            f32x4 a0 = {0.f,0.f,0.f,0.f}, a1 = {0.f,0.f,0.f,0.f}, a2 = {0.f,0.f,0.f,0.f};
            #pragma unroll
            for (int kc = 0; kc < 4; ++kc) {
                bf16x8 bh = *(const bf16x8*)(&Ah[p][ro + kc * 32 + q * 8]);
                a0 = __builtin_amdgcn_mfma_f32_16x16x32_bf16(wregH[0][kc], bh, a0, 0, 0, 0);
                a1 = __builtin_amdgcn_mfma_f32_16x16x32_bf16(wregH[1][kc], bh, a1, 0, 0, 0);
                a2 = __builtin_amdgcn_mfma_f32_16x16x32_bf16(wregH[2][kc], bh, a2, 0, 0, 0);
            }
            f32x4 a3 = {0.f,0.f,0.f,0.f};
#if XK16
            const unsigned short* bxp = (q < 2) ? (AxFS + row * 8 + q * 4)
                                      : (q == 2) ? (AxR + row * 8) : zero16;
            bf16x4 bx = *(const bf16x4*)bxp;
            a0 = __builtin_amdgcn_mfma_f32_16x16x16bf16_1k(wregX[0], bx, a0, 0, 0, 0);
            a1 = __builtin_amdgcn_mfma_f32_16x16x16bf16_1k(wregX[1], bx, a1, 0, 0, 0);
            a2 = __builtin_amdgcn_mfma_f32_16x16x16bf16_1k(wregX[2], bx, a2, 0, 0, 0);
            a3 = __builtin_amdgcn_mfma_f32_16x16x16bf16_1k(wregX[3], bx, a3, 0, 0, 0);
#else
            const unsigned short* bxp = (q == 0) ? (AxFS + row * 8)
                                      : (q == 1) ? (AxR + row * 8) : zero16;
            bf16x8 bx = *(const bf16x8*)bxp;
            a0 = __builtin_amdgcn_mfma_f32_16x16x32_bf16(wregX[0], bx, a0, 0, 0, 0);
            a1 = __builtin_amdgcn_mfma_f32_16x16x32_bf16(wregX[1], bx, a1, 0, 0, 0);
            a2 = __builtin_amdgcn_mfma_f32_16x16x32_bf16(wregX[2], bx, a2, 0, 0, 0);
            a3 = __builtin_amdgcn_mfma_f32_16x16x32_bf16(wregX[3], bx, a3, 0, 0, 0);
#endif

            float hn[4];
            unsigned hp0 = hpk[rl * 2 + 0], hp1 = hpk[rl * 2 + 1];
            #pragma unroll
            for (int rg = 0; rg < 4; ++rg) {
                unsigned hu = (rg < 2) ? hp0 : hp1;
                float ho = ((rg & 1) == 0) ? __uint_as_float(hu << 16)
                                           : __uint_as_float(hu & 0xffff0000u);
                // a0,a1 prescaled by log2e; a2,a3 by 2*log2e (biases folded)
                float rr = __builtin_amdgcn_rcpf(1.0f + exp2f(-a0[rg]));
                float zz = __builtin_amdgcn_rcpf(1.0f + exp2f(-a1[rg]));
                float wv = fmaf(rr, a2[rg], a3[rg]);
                unsigned sg = __float_as_uint(wv) & 0x80000000u;
                float e = exp2f(-fabsf(wv));
                float tv = (1.0f - e) * __builtin_amdgcn_rcpf(1.0f + e);
                tv = __uint_as_float(__float_as_uint(tv) ^ sg);
                hn[rg] = fmaf(zz, ho - tv, tv);
            }
            unsigned pk0 = pkbf(hn[0], hn[1]), pk1 = pkbf(hn[2], hn[3]);
            hpk[rl * 2 + 0] = pk0; hpk[rl * 2 + 1] = pk1;
            // fc partial (fp32): this lane's 4 cols, reduce over q
            float pf = hn[0] * fw.x + hn[1] * fw.y + hn[2] * fw.z + hn[3] * fw.w;
            pf += __shfl_xor(pf, 16);
            pf += __shfl_xor(pf, 32);
            u32x2 pk;
            pk[0] = pk0; pk[1] = pk1;
            *(u32x2*)&Ah[p ^ 1][ro + cg * 16 + q * 4] = pk;
            if (q == 0) red_s[row * 9 + cg] = pf;            // stride 9: conflict-free
        }
        __syncthreads();

        // ========== phase 3: xn reduce + dx rebuild ========================
        if (tid < NN) {
            float xn = fcls_f[128];
            #pragma unroll
            for (int c = 0; c < 8; ++c) xn += red_s[tid * 9 + c];
            float dv = 0.f;
            if (t2 >= TH && t2 < TH + TF)
                dv = *(const float*)(stg[p ^ 1] + OFF_DINV + tid * 4);
            dx_s[tid] = make_float2(dv, xn);
            AxR[tid * 8 + 0] = f2bf(xn);
            if (t >= TH) pred[((long)bb * TF + (t - TH)) * NN + tid] = xn;
        }
        __syncthreads();

        if (t == TH - 1)
            load_phase(WaF, fcow, fcob);
        p ^= 1;
    }
}

extern "C" void kernel_launch(void* const* d_in, const int* in_sizes, int n_in,
                              void* d_out, int out_size, void* d_ws, size_t ws_size,
                              hipStream_t stream) {
    const float* feature = (const float*)d_in[0];
    const float* pm25    = (const float*)d_in[1];
    const float* adj     = (const float*)d_in[2];
    const float* angles  = (const float*)d_in[3];
    const float* W_ih_h  = (const float*)d_in[4];
    const float* W_hh_h  = (const float*)d_in[5];
    const float* b_ih_h  = (const float*)d_in[6];
    const float* b_hh_h  = (const float*)d_in[7];
    const float* fch_w   = (const float*)d_in[8];
    const float* fch_b   = (const float*)d_in[9];
    const float* cw0     = (const float*)d_in[10];
    const float* cw1     = (const float*)d_in[11];
    const float* cbb     = (const float*)d_in[12];
    const float* W_ih    = (const float*)d_in[13];
    const float* W_hh    = (const float*)d_in[14];
    const float* b_ih    = (const float*)d_in[15];
    const float* b_hh    = (const float*)d_in[16];
    const float* fco_w   = (const float*)d_in[17];
    const float* fco_b   = (const float*)d_in[18];
    float* pred = (float*)d_out;

    char* ws = (char*)d_ws;
    size_t off = 0;
    unsigned short* WaH   = (unsigned short*)(ws + off); off += (size_t)NG * KA * 2;   //   163,840
    unsigned short* WaF   = (unsigned short*)(ws + off); off += (size_t)NG * KA * 2;
    float4*         edges = (float4*)(ws + off);         off += (size_t)NN * NN * 16;  //   541,696
    int*            cnt   = (int*)(ws + off);            off += 16;
    char*           xrec  = (char*)(ws + off);
    off += (size_t)BB * ((size_t)TH * REC_H + (size_t)TF * REC_F);                     // 72,351,744

    hipMemsetAsync(cnt, 0, 16, stream);
    prep_weights<<<(NG * KA + 255) / 256, 256, 0, stream>>>(
        W_hh_h, W_ih_h, W_hh, W_ih, b_ih_h, b_hh_h, b_ih, b_hh, WaH, WaF);
    prep_edges<<<(NN * NN + 255) / 256, 256, 0, stream>>>(angles, adj, edges, cnt);
    prep_graph<<<BB, 256, 0, stream>>>(
        feature, pm25, edges, cnt, cw0, cw1, cbb, xrec);

    fused_dgc<<<BB, NT, 0, stream>>>(
        WaH, WaF, fch_w, fch_b, fco_w, fco_b, cw0, cw1, xrec, pred);
}

// Round 4
// 691.653 us; speedup vs baseline: 1.1109x; 1.1109x over previous
//
#include <hip/hip_runtime.h>
#include <hip/hip_bf16.h>
#include <math.h>

#define BB 256
#define NN 184
#define HH 128
#define FF 8
#define TH 24
#define TF 24
#define KA 160       // augmented K (128 h + x block + pad; k=139 = bias col)
#define NG 512       // 4 gate-parts x 128
#define RPAD 192     // padded row count (12 tiles of 16)
#define STRH 136     // Ah row stride (elems)
#define NT 1024      // 16 waves, 4/SIMD
#define NW3 552      // mask words per (b,t)
#define LOG2E 1.44269504088896f

// per-(b,t) staging record, 16B-granular, layout mirrored in LDS:
//   fore: [mask 552*8 = 4416][dinv 184*4 = 736][G 184*4 = 736][AxF 184*16 = 2944] = 8832
//   hist: [AxF 2944]  (loaded at LDS offset OFF_AXF)
#define REC_F 8832
#define REC_H 2944
#define OFF_DINV 4416
#define OFF_G 5152
#define OFF_AXF 5888

typedef __attribute__((ext_vector_type(8))) short bf16x8;
typedef __attribute__((ext_vector_type(4))) short bf16x4;
typedef __attribute__((ext_vector_type(4))) float f32x4;
typedef __attribute__((ext_vector_type(2))) unsigned u32x2;

#if __has_builtin(__builtin_amdgcn_mfma_f32_16x16x16bf16_1k)
#define XK16 1
#else
#define XK16 0
#endif

__host__ __device__ __forceinline__ long recOff(int b, int t) {
    const long PB = (long)TH * REC_H + (long)TF * REC_F;
    return (long)b * PB + ((t < TH) ? (long)t * REC_H
                                    : (long)TH * REC_H + (long)(t - TH) * REC_F);
}

__device__ __forceinline__ unsigned short f2bf(float f) {
    unsigned u = __float_as_uint(f);
    u += 0x7fffu + ((u >> 16) & 1u);
    return (unsigned short)(u >> 16);
}
__device__ __forceinline__ unsigned pkbf(float a, float b) {
    __hip_bfloat162 h = __float22bfloat162_rn(make_float2(a, b));
    return *reinterpret_cast<unsigned*>(&h);
}
__device__ __forceinline__ void gload16(const void* src, void* dst) {
    __builtin_amdgcn_global_load_lds(
        (const __attribute__((address_space(1))) unsigned int*)src,
        (__attribute__((address_space(3))) unsigned int*)dst, 16, 0, 0);
}

// ---------------------------------------------------------------------------
// Augmented bf16 weights Wa[512][160] (R, Z, NH, NX), PRESCALED:
//   R,Z rows (incl. bias col 139) * log2e      -> sigmoid = rcp(1+exp2(-a))
//   NH,NX rows (incl. bias cols)  * 2*log2e    -> tanh via exp2(-|w|)
// X-block slots (k-128): 0..7 = features (hist: slot0 = p), 8 = xn, 9 = g,
// 11 = bias (pairs with const-1 in AxR[3]). All x-slots fit in K=16.
// ---------------------------------------------------------------------------
__global__ void prep_weights(const float* __restrict__ WhhH, const float* __restrict__ WihH,
                             const float* __restrict__ WhhF, const float* __restrict__ WihF,
                             const float* __restrict__ bihH, const float* __restrict__ bhhH,
                             const float* __restrict__ bihF, const float* __restrict__ bhhF,
                             unsigned short* __restrict__ WaH, unsigned short* __restrict__ WaF) {
    int idx = blockIdx.x * 256 + threadIdx.x;
    if (idx >= NG * KA) return;
    int jp = idx / KA, k = idx % KA;
    int j = jp & 127, part = jp >> 7;
    float vh = 0.f, vf = 0.f;
    if (part <= 1) {              // R, Z
        int row = part * 128 + j;
        if (k < 128) { vh = WhhH[row * 128 + k]; vf = WhhF[row * 128 + k]; }
        else {
            int s = k - 128;
            if (s == 0)  vh = WihH[row * 2 + 1];
            if (s < 8)   vf = WihF[row * 10 + (s + 1)];
            if (s == 8)  { vh = WihH[row * 2 + 0]; vf = WihF[row * 10 + 0]; }
            if (s == 9)  vf = WihF[row * 10 + 9];
            if (s == 11) { vh = bihH[row] + bhhH[row]; vf = bihF[row] + bhhF[row]; }
        }
    } else if (part == 2) {       // NH: h part of n-gate + bhh at bias col
        if (k < 128) { vh = WhhH[(256 + j) * 128 + k]; vf = WhhF[(256 + j) * 128 + k]; }
        else if (k == 139) { vh = bhhH[256 + j]; vf = bhhF[256 + j]; }
    } else {                      // NX: x part of n-gate | bih@139
        if (k >= 128) {
            int s = k - 128;
            if (s == 0)  vh = WihH[(256 + j) * 2 + 1];
            if (s < 8)   vf = WihF[(256 + j) * 10 + (s + 1)];
            if (s == 8)  { vh = WihH[(256 + j) * 2 + 0]; vf = WihF[(256 + j) * 10 + 0]; }
            if (s == 9)  vf = WihF[(256 + j) * 10 + 9];
            if (s == 11) { vh = bihH[256 + j]; vf = bihF[256 + j]; }
        }
    }
    float sc = (part <= 1) ? LOG2E : 2.0f * LOG2E;
    WaH[idx] = f2bf(vh * sc);
    WaF[idx] = f2bf(vf * sc);
}

// ---------------------------------------------------------------------------
// Sparse edge list over adj: rec = (c1, c2, i, j) as float4.
// ---------------------------------------------------------------------------
__global__ void prep_edges(const float* __restrict__ angles, const float* __restrict__ adj,
                           float4* __restrict__ edges, int* __restrict__ cnt) {
    int idx = blockIdx.x * 256 + threadIdx.x;
    if (idx < NN * NN && adj[idx] > 0.f) {
        float a = angles[idx];
        int pos = atomicAdd(cnt, 1);
        float4 r;
        r.x = cosf(a);
        r.y = cosf(a - 1.57079632679489662f);
        r.z = __int_as_float(idx / NN);   // i (source)
        r.w = __int_as_float(idx % NN);   // j (dest)
        edges[pos] = r;
    }
}

// ---------------------------------------------------------------------------
// Record builder: one block per (batch, step) -- full grid parallelism
// (round-3's per-batch serial t-loop regressed; edges are L2-resident so
// re-reads are cheap). The per-j G gather is word-parallel: 552 (j,word)
// tasks with 8-channel partials in LDS, then a per-j combine.
// ---------------------------------------------------------------------------
__global__ __launch_bounds__(256) void prep_graph(
    const float* __restrict__ feature, const float* __restrict__ pm25,
    const float4* __restrict__ edges, const int* __restrict__ ecnt,
    const float* __restrict__ cw0, const float* __restrict__ cw1,
    const float* __restrict__ cbb, char* __restrict__ xrec)
{
    const int bt = blockIdx.x;
    const int b = bt / (TH + TF), tt = bt % (TH + TF);
    const int tid = threadIdx.x;

    char* rec = xrec + recOff(b, tt);
    if (tt < TH) {
        if (tid < NN) {
            unsigned short pb = f2bf(pm25[((long)b * TH + tt) * NN + tid]);
            uint4* dst = (uint4*)rec + tid;
            *dst = make_uint4((unsigned)pb, 0u, 0u, 0u);
        }
        return;
    }

    __shared__ float f8[NN * FF];                   //  5,888 B
    __shared__ unsigned long long mT[NN][3];        //  4,416 B
    __shared__ int dg[NN];                          //    736 B
    __shared__ float di[NN];                        //    736 B
    __shared__ float red[NW3][8];                   // 17,664 B

    const float4* fb4 = (const float4*)(feature + ((long)b * (TH + TF) + tt) * (NN * FF));
    for (int i = tid; i < (NN * FF) / 4; i += 256) ((float4*)f8)[i] = fb4[i];
    for (int i = tid; i < NN * 3; i += 256) ((unsigned long long*)mT)[i] = 0ull;
    for (int i = tid; i < NN; i += 256) dg[i] = 0;
    __syncthreads();
    const int nE = *ecnt;
    for (int e = tid; e < nE; e += 256) {
        float4 r = edges[e];
        int ii = __float_as_int(r.z), jj = __float_as_int(r.w);
        if (f8[ii * FF] * r.x + f8[ii * FF + 1] * r.y >= 0.5f) {
            atomicAdd(&dg[ii], 1);
            atomicOr(&mT[jj][ii >> 6], 1ull << (ii & 63));
        }
    }
    __syncthreads();
    if (tid < NN) di[tid] = (dg[tid] > 0) ? rsqrtf((float)dg[tid]) : 0.f;
    __syncthreads();
    // mask words out (independent of gather)
    unsigned long long* mr = (unsigned long long*)rec;
    for (int i = tid; i < NW3; i += 256) mr[i] = ((const unsigned long long*)mT)[i];
    // word-parallel 8-channel gather
    for (int task = tid; task < NW3; task += 256) {
        int j = task / 3, wd = task - j * 3;
        unsigned long long m = mT[j][wd];
        float acc[8];
        #pragma unroll
        for (int c = 0; c < 8; ++c) acc[c] = 0.f;
        while (m) {
            int bp = __ffsll(m) - 1; m &= m - 1;
            int i = wd * 64 + bp;
            float d = di[i];
            #pragma unroll
            for (int c = 0; c < 8; ++c) acc[c] += d * f8[i * FF + c];
        }
        #pragma unroll
        for (int c = 0; c < 8; ++c) red[task][c] = acc[c];
    }
    __syncthreads();
    if (tid < NN) {
        int j = tid;
        float dj = di[j];
        float hzj = (dj > 0.f) ? 0.f : -1.f;
        float G = cbb[0];
        #pragma unroll
        for (int c = 0; c < 8; ++c) {
            float accc = red[j * 3 + 0][c] + red[j * 3 + 1][c] + red[j * 3 + 2][c];
            float xv = f8[j * FF + c];
            float y = -dj * accc + hzj * xv;
            G += xv * cw0[c + 1] + y * cw1[c + 1];
        }
        ((float*)(rec + OFF_DINV))[j] = dj;
        ((float*)(rec + OFF_G))[j] = G;
        unsigned short* ax = (unsigned short*)(rec + OFF_AXF) + j * 8;
        #pragma unroll
        for (int c = 0; c < 8; ++c) ax[c] = f2bf(f8[j * FF + c]);
    }
}

// ---------------------------------------------------------------------------
// Persistent fused kernel: one block per batch, 1024 threads (16 waves,
// 4/SIMD, 128-VGPR cap). Register diet v2: h_old is NOT kept in registers --
// it is read back from Ah[p] (the same wave wrote those bf16 values there
// last step; identical bits, one ds_read_b64 per row-tile, latency hidden
// under the MFMA chain). Eliminates the hpk[12] array -> peak demand < 128,
// zero spills expected (verify: WRITE_SIZE ~= pred bytes).
// ---------------------------------------------------------------------------
__global__ __launch_bounds__(NT, 4) void fused_dgc(
    const unsigned short* __restrict__ WaH,
    const unsigned short* __restrict__ WaF,
    const float* __restrict__ fchw, const float* __restrict__ fchb,
    const float* __restrict__ fcow, const float* __restrict__ fcob,
    const float* __restrict__ cw0, const float* __restrict__ cw1,
    const char* __restrict__ xrec,
    float* __restrict__ pred)
{
    __shared__ unsigned short Ah[2][RPAD * STRH];   // 104,448 B
    __shared__ unsigned short AxR[RPAD * 8];        //   3,072 B (xn, g, -, 1.0, 0..)
    __shared__ __align__(16) char stg[2][8960];     //  17,920 B
    __shared__ float red_s[RPAD * 9];               //   6,912 B (fc partials)
    __shared__ float2 dx_s[NN];                     //   1,472 B (.x = dinv, .y = xn)
    __shared__ float fcls_f[132];                   //     528 B (fc w fp32 + bias@128)
    __shared__ unsigned short zero16[8];            //      16 B

    const int tid = threadIdx.x;
    const int bb = blockIdx.x;
    const int w = tid >> 6, lane = tid & 63, q = lane >> 4, lq = lane & 15;
    const int cg = w & 7, rh = w >> 3;

    for (int i = tid; i < RPAD * STRH; i += NT) Ah[0][i] = 0;
    for (int i = tid; i < RPAD * 8; i += NT)
        AxR[i] = ((i & 7) == 3) ? (unsigned short)0x3F80 : (unsigned short)0;
    if (tid < 8) zero16[tid] = 0;
    if (tid < NN) dx_s[tid] = make_float2(0.f, 0.f);

    // ---- phase weights in registers ----
    bf16x8 wregH[3][4];   // g = R,Z,NH : kc 0..3 (h part)
#if XK16
    bf16x4 wregX[4];      // g = R,Z,NH,NX : x block, K=16
#else
    bf16x8 wregX[4];      // K=32 fallback
#endif
    auto load_phase = [&](const unsigned short* Wa, const float* fcw, const float* fcb) {
        const int jcol = cg * 16 + lq;
        #pragma unroll
        for (int g = 0; g < 3; ++g)
            #pragma unroll
            for (int kc = 0; kc < 4; ++kc)
                wregH[g][kc] = *(const bf16x8*)(Wa + (long)(g * 128 + jcol) * KA + kc * 32 + q * 8);
        #pragma unroll
        for (int g = 0; g < 4; ++g)
#if XK16
            wregX[g] = *(const bf16x4*)(Wa + (long)(g * 128 + jcol) * KA + 128 + q * 4);
#else
            wregX[g] = *(const bf16x8*)(Wa + (long)(g * 128 + jcol) * KA + 128 + q * 8);
#endif
        if (tid < 132) fcls_f[tid] = (tid < 128) ? fcw[tid] : ((tid == 128) ? fcb[0] : 0.f);
    };
    load_phase(WaH, fchw, fchb);

    // ---- stage t=0 record ----
    if (tid < NN)
        gload16(xrec + recOff(bb, 0) + (long)tid * 16,
                (char*)stg[0] + OFF_AXF + (tid & ~63) * 16);

    const float w00 = cw0[0], w10 = cw1[0];

    int p = 0;
    __syncthreads();       // init + stage(0) visible

    for (int t = 0; t < TH + TF; ++t) {
        const unsigned long long* maskS = (const unsigned long long*)stg[p];
        const float* GS = (const float*)(stg[p] + OFF_G);
        const unsigned short* AxFS = (const unsigned short*)(stg[p] + OFF_AXF);

        // ============ cheb gate (fore): gather + finalize in ONE phase =====
        if (t >= TH) {
            const int jg = tid >> 2, wd = tid & 3;
            if (jg < NN) {
                unsigned long long m = (wd < 3) ? maskS[jg * 3 + wd] : 0ull;
                float acc = 0.f;
                while (m) {
                    int bp = __ffsll(m) - 1; m &= m - 1;
                    float2 dxv = dx_s[wd * 64 + bp];
                    acc += dxv.x * dxv.y;
                }
                acc += __shfl_xor(acc, 1);
                acc += __shfl_xor(acc, 2);
                if (wd == 0) {
                    float2 dxj = dx_s[jg];
                    float hzj = (dxj.x > 0.f) ? 0.f : -1.f;
                    float y0 = -dxj.x * acc + hzj * dxj.y;
                    float pre = GS[jg] + dxj.y * w00 + y0 * w10;
                    float g = __builtin_amdgcn_rcpf(1.0f + exp2f(-LOG2E * pre));
                    AxR[jg * 8 + 1] = f2bf(g);
                }
            }
            __syncthreads();
        }

        // ====== issue t+1 staging (async global->LDS, lands by next bar) ===
        const int t2 = t + 1;
        if (t2 < TH + TF) {
            const int nch = (t2 < TH) ? NN : NW3;
            if (tid < nch)
                gload16(xrec + recOff(bb, t2) + (long)tid * 16,
                        (char*)stg[p ^ 1] + ((t2 < TH) ? OFF_AXF : 0) + (tid & ~63) * 16);
        }

        // ========== GRU GEMM + epilogue + fc partials (6 row-tiles) ========
        f32x4 fw = *(const f32x4*)&fcls_f[cg * 16 + q * 4];
        #pragma unroll
        for (int rl = 0; rl < 6; ++rl) {
            const int row = rh * 96 + rl * 16 + lq;
            const int ro = row * STRH;
            f32x4 a0 = {0.f,0.f,0.f,0.f}, a1 = {0.f,0.f,0.f,0.f}, a2 = {0.f,0.f,0.f,0.f};
            #pragma unroll
            for (int kc = 0; kc < 4; ++kc) {
                bf16x8 bh = *(const bf16x8*)(&Ah[p][ro + kc * 32 + q * 8]);
                a0 = __builtin_amdgcn_mfma_f32_16x16x32_bf16(wregH[0][kc], bh, a0, 0, 0, 0);
                a1 = __builtin_amdgcn_mfma_f32_16x16x32_bf16(wregH[1][kc], bh, a1, 0, 0, 0);
                a2 = __builtin_amdgcn_mfma_f32_16x16x32_bf16(wregH[2][kc], bh, a2, 0, 0, 0);
            }
            f32x4 a3 = {0.f,0.f,0.f,0.f};
#if XK16
            const unsigned short* bxp = (q < 2) ? (AxFS + row * 8 + q * 4)
                                      : (q == 2) ? (AxR + row * 8) : zero16;
            bf16x4 bx = *(const bf16x4*)bxp;
            a0 = __builtin_amdgcn_mfma_f32_16x16x16bf16_1k(wregX[0], bx, a0, 0, 0, 0);
            a1 = __builtin_amdgcn_mfma_f32_16x16x16bf16_1k(wregX[1], bx, a1, 0, 0, 0);
            a2 = __builtin_amdgcn_mfma_f32_16x16x16bf16_1k(wregX[2], bx, a2, 0, 0, 0);
            a3 = __builtin_amdgcn_mfma_f32_16x16x16bf16_1k(wregX[3], bx, a3, 0, 0, 0);
#else
            const unsigned short* bxp = (q == 0) ? (AxFS + row * 8)
                                      : (q == 1) ? (AxR + row * 8) : zero16;
            bf16x8 bx = *(const bf16x8*)bxp;
            a0 = __builtin_amdgcn_mfma_f32_16x16x32_bf16(wregX[0], bx, a0, 0, 0, 0);
            a1 = __builtin_amdgcn_mfma_f32_16x16x32_bf16(wregX[1], bx, a1, 0, 0, 0);
            a2 = __builtin_amdgcn_mfma_f32_16x16x32_bf16(wregX[2], bx, a2, 0, 0, 0);
            a3 = __builtin_amdgcn_mfma_f32_16x16x32_bf16(wregX[3], bx, a3, 0, 0, 0);
#endif

            // h_old readback (same bf16 this wave wrote last step)
            u32x2 hold = *(const u32x2*)&Ah[p][ro + cg * 16 + q * 4];

            float hn[4];
            #pragma unroll
            for (int rg = 0; rg < 4; ++rg) {
                unsigned hu = hold[rg >> 1];
                float ho = ((rg & 1) == 0) ? __uint_as_float(hu << 16)
                                           : __uint_as_float(hu & 0xffff0000u);
                // a0,a1 prescaled by log2e; a2,a3 by 2*log2e (biases folded)
                float rr = __builtin_amdgcn_rcpf(1.0f + exp2f(-a0[rg]));
                float zz = __builtin_amdgcn_rcpf(1.0f + exp2f(-a1[rg]));
                float wv = fmaf(rr, a2[rg], a3[rg]);
                unsigned sg = __float_as_uint(wv) & 0x80000000u;
                float e = exp2f(-fabsf(wv));
                float tv = (1.0f - e) * __builtin_amdgcn_rcpf(1.0f + e);
                tv = __uint_as_float(__float_as_uint(tv) ^ sg);
                hn[rg] = fmaf(zz, ho - tv, tv);
            }
            // fc partial (fp32): this lane's 4 cols, reduce over q
            float pf = hn[0] * fw.x + hn[1] * fw.y + hn[2] * fw.z + hn[3] * fw.w;
            pf += __shfl_xor(pf, 16);
            pf += __shfl_xor(pf, 32);
            u32x2 pk;
            pk[0] = pkbf(hn[0], hn[1]);
            pk[1] = pkbf(hn[2], hn[3]);
            *(u32x2*)&Ah[p ^ 1][ro + cg * 16 + q * 4] = pk;
            if (q == 0) red_s[row * 9 + cg] = pf;            // stride 9: conflict-free
        }
        __syncthreads();

        // ========== phase 3: xn reduce + dx rebuild ========================
        if (tid < NN) {
            float xn = fcls_f[128];
            #pragma unroll
            for (int c = 0; c < 8; ++c) xn += red_s[tid * 9 + c];
            float dv = 0.f;
            if (t2 >= TH && t2 < TH + TF)
                dv = *(const float*)(stg[p ^ 1] + OFF_DINV + tid * 4);
            dx_s[tid] = make_float2(dv, xn);
            AxR[tid * 8 + 0] = f2bf(xn);
            if (t >= TH) pred[((long)bb * TF + (t - TH)) * NN + tid] = xn;
        }
        __syncthreads();

        if (t == TH - 1)
            load_phase(WaF, fcow, fcob);
        p ^= 1;
    }
}

extern "C" void kernel_launch(void* const* d_in, const int* in_sizes, int n_in,
                              void* d_out, int out_size, void* d_ws, size_t ws_size,
                              hipStream_t stream) {
    const float* feature = (const float*)d_in[0];
    const float* pm25    = (const float*)d_in[1];
    const float* adj     = (const float*)d_in[2];
    const float* angles  = (const float*)d_in[3];
    const float* W_ih_h  = (const float*)d_in[4];
    const float* W_hh_h  = (const float*)d_in[5];
    const float* b_ih_h  = (const float*)d_in[6];
    const float* b_hh_h  = (const float*)d_in[7];
    const float* fch_w   = (const float*)d_in[8];
    const float* fch_b   = (const float*)d_in[9];
    const float* cw0     = (const float*)d_in[10];
    const float* cw1     = (const float*)d_in[11];
    const float* cbb     = (const float*)d_in[12];
    const float* W_ih    = (const float*)d_in[13];
    const float* W_hh    = (const float*)d_in[14];
    const float* b_ih    = (const float*)d_in[15];
    const float* b_hh    = (const float*)d_in[16];
    const float* fco_w   = (const float*)d_in[17];
    const float* fco_b   = (const float*)d_in[18];
    float* pred = (float*)d_out;

    char* ws = (char*)d_ws;
    size_t off = 0;
    unsigned short* WaH   = (unsigned short*)(ws + off); off += (size_t)NG * KA * 2;   //   163,840
    unsigned short* WaF   = (unsigned short*)(ws + off); off += (size_t)NG * KA * 2;
    float4*         edges = (float4*)(ws + off);         off += (size_t)NN * NN * 16;  //   541,696
    int*            cnt   = (int*)(ws + off);            off += 16;
    char*           xrec  = (char*)(ws + off);
    off += (size_t)BB * ((size_t)TH * REC_H + (size_t)TF * REC_F);                     // 72,351,744

    hipMemsetAsync(cnt, 0, 16, stream);
    prep_weights<<<(NG * KA + 255) / 256, 256, 0, stream>>>(
        W_hh_h, W_ih_h, W_hh, W_ih, b_ih_h, b_hh_h, b_ih, b_hh, WaH, WaF);
    prep_edges<<<(NN * NN + 255) / 256, 256, 0, stream>>>(angles, adj, edges, cnt);
    prep_graph<<<BB * (TH + TF), 256, 0, stream>>>(
        feature, pm25, edges, cnt, cw0, cw1, cbb, xrec);

    fused_dgc<<<BB, NT, 0, stream>>>(
        WaH, WaF, fch_w, fch_b, fco_w, fco_b, cw0, cw1, xrec, pred);
}

// Round 5
// 644.994 us; speedup vs baseline: 1.1912x; 1.0723x over previous
//
#include <hip/hip_runtime.h>
#include <hip/hip_bf16.h>
#include <math.h>

#define BB 256
#define NN 184
#define HH 128
#define FF 8
#define TH 24
#define TF 24
#define KA 160       // augmented K (128 h + x block + pad; k=139 = bias col)
#define NG2 640      // 5 gate-parts x 128 (R, Z, NH, NX, NXH)
#define RPAD 192     // padded row count (12 tiles of 16)
#define STRH 136     // Ah row stride (elems)
#define NT 1024      // 16 waves, 4/SIMD
#define NW3 552      // mask words per (b,t)
#define LOG2E 1.44269504088896f

// per-(b,fore-t) staging record, 16B-granular, layout mirrored in LDS:
//   [mask 552*8 = 4416][dinv 184*4 = 736][G 184*4 = 736][AxF 184*16 = 2944] = 8832
#define REC_F 8832
#define OFF_DINV 4416
#define OFF_G 5152
#define OFF_AXF 5888

typedef __attribute__((ext_vector_type(8))) short bf16x8;
typedef __attribute__((ext_vector_type(4))) short bf16x4;
typedef __attribute__((ext_vector_type(4))) float f32x4;
typedef __attribute__((ext_vector_type(2))) unsigned u32x2;

#if __has_builtin(__builtin_amdgcn_mfma_f32_16x16x16bf16_1k)
#define XK16 1
#else
#define XK16 0
#endif

#if __has_builtin(__builtin_amdgcn_exp2f)
#define EXP2(x) __builtin_amdgcn_exp2f(x)
#else
#define EXP2(x) exp2f(x)
#endif

__device__ __forceinline__ unsigned short f2bf(float f) {
    unsigned u = __float_as_uint(f);
    u += 0x7fffu + ((u >> 16) & 1u);
    return (unsigned short)(u >> 16);
}
__device__ __forceinline__ unsigned pkbf(float a, float b) {
    __hip_bfloat162 h = __float22bfloat162_rn(make_float2(a, b));
    return *reinterpret_cast<unsigned*>(&h);
}
__device__ __forceinline__ void gload16(const void* src, void* dst) {
    __builtin_amdgcn_global_load_lds(
        (const __attribute__((address_space(1))) unsigned int*)src,
        (__attribute__((address_space(3))) unsigned int*)dst, 16, 0, 0);
}

// ---------------------------------------------------------------------------
// Augmented bf16 weights Wa[640][160] (R, Z, NH, NX, NXH), PRESCALED:
//   R,Z rows * log2e ; NH,NX,NXH rows * 2*log2e.
// HIST (WaH) xn-FOLDING: xn_t = fcw.h_t + fcb is linear in h ->
//   R,Z,(NX via part4) h-parts get + W_xn (x) fcw  (rank-1), biases get
//   + W_xn*fcb. Part 4 (NXH) is the n-gate's xn rank-1 h-part (hist only).
// X-block slots (k-128): 0..7 = features (hist: slot0 = p), 8 = xn (fore;
// hist: t=0 correction -fcb), 9 = g, 11 = bias (pairs with const-1).
// ---------------------------------------------------------------------------
__global__ void prep_weights(const float* __restrict__ WhhH, const float* __restrict__ WihH,
                             const float* __restrict__ WhhF, const float* __restrict__ WihF,
                             const float* __restrict__ bihH, const float* __restrict__ bhhH,
                             const float* __restrict__ bihF, const float* __restrict__ bhhF,
                             const float* __restrict__ fchw, const float* __restrict__ fchb,
                             unsigned short* __restrict__ WaH, unsigned short* __restrict__ WaF) {
    int idx = blockIdx.x * 256 + threadIdx.x;
    if (idx >= NG2 * KA) return;
    int jp = idx / KA, k = idx % KA;
    int j = jp & 127, part = jp >> 7;
    float vh = 0.f, vf = 0.f;
    if (part <= 1) {              // R, Z
        int row = part * 128 + j;
        if (k < 128) {
            vh = WhhH[row * 128 + k] + WihH[row * 2 + 0] * fchw[k];   // xn fold
            vf = WhhF[row * 128 + k];
        } else {
            int s = k - 128;
            if (s == 0)  vh = WihH[row * 2 + 1];                      // p
            if (s < 8)   vf = WihF[row * 10 + (s + 1)];
            if (s == 8)  { vh = WihH[row * 2 + 0]; vf = WihF[row * 10 + 0]; }
            if (s == 9)  vf = WihF[row * 10 + 9];
            if (s == 11) {
                vh = bihH[row] + bhhH[row] + WihH[row * 2 + 0] * fchb[0];
                vf = bihF[row] + bhhF[row];
            }
        }
    } else if (part == 2) {       // NH: h part of n-gate + bhh at bias col
        if (k < 128) { vh = WhhH[(256 + j) * 128 + k]; vf = WhhF[(256 + j) * 128 + k]; }
        else if (k == 139) { vh = bhhH[256 + j]; vf = bhhF[256 + j]; }
    } else if (part == 3) {       // NX: x part of n-gate | bih@139
        if (k >= 128) {
            int s = k - 128;
            if (s == 0)  vh = WihH[(256 + j) * 2 + 1];
            if (s < 8)   vf = WihF[(256 + j) * 10 + (s + 1)];
            if (s == 8)  { vh = WihH[(256 + j) * 2 + 0]; vf = WihF[(256 + j) * 10 + 0]; }
            if (s == 9)  vf = WihF[(256 + j) * 10 + 9];
            if (s == 11) {
                vh = bihH[256 + j] + WihH[(256 + j) * 2 + 0] * fchb[0];
                vf = bihF[256 + j];
            }
        }
    } else {                      // NXH: rank-1 W_xn(n) (x) fcw, hist only
        if (k < 128) vh = WihH[(256 + j) * 2 + 0] * fchw[k];
    }
    float sc = (part <= 1) ? LOG2E : 2.0f * LOG2E;
    WaH[idx] = f2bf(vh * sc);
    WaF[idx] = f2bf(vf * sc);
}

// ---------------------------------------------------------------------------
// Sparse edge list over adj: rec = (c1, c2, i, j) as float4.
// ---------------------------------------------------------------------------
__global__ void prep_edges(const float* __restrict__ angles, const float* __restrict__ adj,
                           float4* __restrict__ edges, int* __restrict__ cnt) {
    int idx = blockIdx.x * 256 + threadIdx.x;
    if (idx < NN * NN && adj[idx] > 0.f) {
        float a = angles[idx];
        int pos = atomicAdd(cnt, 1);
        float4 r;
        r.x = cosf(a);
        r.y = cosf(a - 1.57079632679489662f);
        r.z = __int_as_float(idx / NN);   // i (source)
        r.w = __int_as_float(idx % NN);   // j (dest)
        edges[pos] = r;
    }
}

// ---------------------------------------------------------------------------
// Record builder: one block per (batch, step). Hist blocks just transpose
// pm25 into the compact bf16 phist block. Fore blocks build bitmask, dinv,
// G, AxF (word-parallel gather).
// ---------------------------------------------------------------------------
__global__ __launch_bounds__(256) void prep_graph(
    const float* __restrict__ feature, const float* __restrict__ pm25,
    const float4* __restrict__ edges, const int* __restrict__ ecnt,
    const float* __restrict__ cw0, const float* __restrict__ cw1,
    const float* __restrict__ cbb, char* __restrict__ xrec,
    unsigned short* __restrict__ phist)
{
    const int bt = blockIdx.x;
    const int b = bt / (TH + TF), tt = bt % (TH + TF);
    const int tid = threadIdx.x;

    if (tt < TH) {
        if (tid < NN)
            phist[(long)b * (TH * NN) + tt * NN + tid] =
                f2bf(pm25[((long)b * TH + tt) * NN + tid]);
        return;
    }

    char* rec = xrec + ((long)b * TF + (tt - TH)) * REC_F;

    __shared__ float f8[NN * FF];                   //  5,888 B
    __shared__ unsigned long long mT[NN][3];        //  4,416 B
    __shared__ int dg[NN];                          //    736 B
    __shared__ float di[NN];                        //    736 B
    __shared__ float red[NW3][8];                   // 17,664 B

    const float4* fb4 = (const float4*)(feature + ((long)b * (TH + TF) + tt) * (NN * FF));
    for (int i = tid; i < (NN * FF) / 4; i += 256) ((float4*)f8)[i] = fb4[i];
    for (int i = tid; i < NN * 3; i += 256) ((unsigned long long*)mT)[i] = 0ull;
    for (int i = tid; i < NN; i += 256) dg[i] = 0;
    __syncthreads();
    const int nE = *ecnt;
    for (int e = tid; e < nE; e += 256) {
        float4 r = edges[e];
        int ii = __float_as_int(r.z), jj = __float_as_int(r.w);
        if (f8[ii * FF] * r.x + f8[ii * FF + 1] * r.y >= 0.5f) {
            atomicAdd(&dg[ii], 1);
            atomicOr(&mT[jj][ii >> 6], 1ull << (ii & 63));
        }
    }
    __syncthreads();
    if (tid < NN) di[tid] = (dg[tid] > 0) ? rsqrtf((float)dg[tid]) : 0.f;
    __syncthreads();
    unsigned long long* mr = (unsigned long long*)rec;
    for (int i = tid; i < NW3; i += 256) mr[i] = ((const unsigned long long*)mT)[i];
    for (int task = tid; task < NW3; task += 256) {
        int j = task / 3, wd = task - j * 3;
        unsigned long long m = mT[j][wd];
        float acc[8];
        #pragma unroll
        for (int c = 0; c < 8; ++c) acc[c] = 0.f;
        while (m) {
            int bp = __ffsll(m) - 1; m &= m - 1;
            int i = wd * 64 + bp;
            float d = di[i];
            #pragma unroll
            for (int c = 0; c < 8; ++c) acc[c] += d * f8[i * FF + c];
        }
        #pragma unroll
        for (int c = 0; c < 8; ++c) red[task][c] = acc[c];
    }
    __syncthreads();
    if (tid < NN) {
        int j = tid;
        float dj = di[j];
        float hzj = (dj > 0.f) ? 0.f : -1.f;
        float G = cbb[0];
        #pragma unroll
        for (int c = 0; c < 8; ++c) {
            float accc = red[j * 3 + 0][c] + red[j * 3 + 1][c] + red[j * 3 + 2][c];
            float xv = f8[j * FF + c];
            float y = -dj * accc + hzj * xv;
            G += xv * cw0[c + 1] + y * cw1[c + 1];
        }
        ((float*)(rec + OFF_DINV))[j] = dj;
        ((float*)(rec + OFF_G))[j] = G;
        unsigned short* ax = (unsigned short*)(rec + OFF_AXF) + j * 8;
        #pragma unroll
        for (int c = 0; c < 8; ++c) ax[c] = f2bf(f8[j * FF + c]);
    }
}

// ---------------------------------------------------------------------------
// Persistent fused kernel. HIST steps (t < TH): xn folded into weights ->
// pure 4-h-part GEMM + register-built {p, bias} x-frag from the LDS-resident
// pm25 block; ONE barrier, no staging, no fc, no phase 3. FORE steps: cheb
// gather -> bar -> GEMM + fc partials + async record staging -> bar ->
// xn reduce -> bar. fc path also active at t = TH-1 (seeds fore xn).
// ---------------------------------------------------------------------------
__global__ __launch_bounds__(NT, 4) void fused_dgc(
    const unsigned short* __restrict__ WaH,
    const unsigned short* __restrict__ WaF,
    const float* __restrict__ fchw, const float* __restrict__ fchb,
    const float* __restrict__ fcow, const float* __restrict__ fcob,
    const float* __restrict__ cw0, const float* __restrict__ cw1,
    const char* __restrict__ xrec, const unsigned short* __restrict__ phist,
    float* __restrict__ pred)
{
    __shared__ unsigned short Ah[2][RPAD * STRH];   // 104,448 B
    __shared__ unsigned short AxR[RPAD * 8];        //   3,072 B (xn, g, -, 1.0, 0..)
    __shared__ __align__(16) char stg[2][8960];     //  17,920 B
    __shared__ float red_s[RPAD * 9];               //   6,912 B (fc partials)
    __shared__ float2 dx_s[NN];                     //   1,472 B (.x = dinv, .y = xn)
    __shared__ float fcls_f[132];                   //     528 B (fc w fp32 + bias@128)
    __shared__ unsigned short zero16[8];            //      16 B
    __shared__ __align__(16) unsigned short phist_s[TH * NN + 16];  // 8,864 B

    const int tid = threadIdx.x;
    const int bb = blockIdx.x;
    const int w = tid >> 6, lane = tid & 63, q = lane >> 4, lq = lane & 15;
    const int cg = w & 7, rh = w >> 3;

    for (int i = tid; i < RPAD * STRH; i += NT) Ah[0][i] = 0;
    for (int i = tid; i < RPAD * 8; i += NT)
        AxR[i] = ((i & 7) == 3) ? (unsigned short)0x3F80 : (unsigned short)0;
    if (tid < 8) zero16[tid] = 0;
    if (tid < NN) dx_s[tid] = make_float2(0.f, 0.f);

    // ---- phase weights in registers ----
    bf16x8 wregH[4][4];   // parts: R,Z,NH (+NXH hist) : kc 0..3 (h part)
#if XK16
    bf16x4 wregX[4];      // R,Z,NH,NX : x block, K=16
#else
    bf16x8 wregX[4];      // K=32 fallback
#endif
    auto load_w = [&](const unsigned short* Wa, const float* fcw, const float* fcb, bool h4) {
        const int jcol = cg * 16 + lq;
        #pragma unroll
        for (int g = 0; g < 3; ++g)
            #pragma unroll
            for (int kc = 0; kc < 4; ++kc)
                wregH[g][kc] = *(const bf16x8*)(Wa + (long)(g * 128 + jcol) * KA + kc * 32 + q * 8);
        if (h4)
            #pragma unroll
            for (int kc = 0; kc < 4; ++kc)
                wregH[3][kc] = *(const bf16x8*)(Wa + (long)(4 * 128 + jcol) * KA + kc * 32 + q * 8);
        #pragma unroll
        for (int g = 0; g < 4; ++g)
#if XK16
            wregX[g] = *(const bf16x4*)(Wa + (long)(g * 128 + jcol) * KA + 128 + q * 4);
#else
            wregX[g] = *(const bf16x8*)(Wa + (long)(g * 128 + jcol) * KA + 128 + q * 8);
#endif
        if (tid < 132) fcls_f[tid] = (tid < 128) ? fcw[tid] : ((tid == 128) ? fcb[0] : 0.f);
    };
    load_w(WaH, fchw, fchb, true);

    // ---- stage the full pm25 block (8832 B, once) ----
    if (tid < NW3)
        gload16((const char*)phist + (long)bb * (TH * NN * 2) + tid * 16,
                (char*)phist_s + (tid & ~63) * 16);

    const float w00 = cw0[0], w10 = cw1[0];
    const float fcbH = fchb[0];

    int p = 0;
    __syncthreads();       // init + phist visible

    for (int t = 0; t < TH + TF; ++t) {
        const bool hist = (t < TH);
        const bool dofc = (t >= TH - 1);
        const unsigned short* AxFS = (const unsigned short*)(stg[p] + OFF_AXF);

        // ============ cheb gate (fore): gather + finalize in ONE phase =====
        if (!hist) {
            const unsigned long long* maskS = (const unsigned long long*)stg[p];
            const float* GS = (const float*)(stg[p] + OFF_G);
            const int jg = tid >> 2, wd = tid & 3;
            if (jg < NN) {
                unsigned long long m = (wd < 3) ? maskS[jg * 3 + wd] : 0ull;
                float acc = 0.f;
                while (m) {
                    int bp = __ffsll(m) - 1; m &= m - 1;
                    float2 dxv = dx_s[wd * 64 + bp];
                    acc += dxv.x * dxv.y;
                }
                acc += __shfl_xor(acc, 1);
                acc += __shfl_xor(acc, 2);
                if (wd == 0) {
                    float2 dxj = dx_s[jg];
                    float hzj = (dxj.x > 0.f) ? 0.f : -1.f;
                    float y0 = -dxj.x * acc + hzj * dxj.y;
                    float pre = GS[jg] + dxj.y * w00 + y0 * w10;
                    float g = __builtin_amdgcn_rcpf(1.0f + EXP2(-LOG2E * pre));
                    AxR[jg * 8 + 1] = f2bf(g);
                }
            }
            __syncthreads();
        }

        // ====== issue t+1 fore-record staging (lands by post-GEMM bar) =====
        const int t2 = t + 1;
        if (t2 >= TH && t2 < TH + TF && tid < NW3)
            gload16(xrec + ((long)bb * TF + (t2 - TH)) * REC_F + tid * 16,
                    (char*)stg[p ^ 1] + (tid & ~63) * 16);

        // ========== GRU GEMM + epilogue (+ fc partials if dofc) ============
        f32x4 fw = *(const f32x4*)&fcls_f[cg * 16 + q * 4];
        const unsigned short corr0 = (t == 0) ? f2bf(-fcbH) : (unsigned short)0;
        #pragma unroll
        for (int rl = 0; rl < 6; ++rl) {
            const int row = rh * 96 + rl * 16 + lq;
            const int ro = row * STRH;
            f32x4 a0 = {0.f,0.f,0.f,0.f}, a1 = {0.f,0.f,0.f,0.f}, a2 = {0.f,0.f,0.f,0.f};
            f32x4 a3 = {0.f,0.f,0.f,0.f};
            #pragma unroll
            for (int kc = 0; kc < 4; ++kc) {
                bf16x8 bh = *(const bf16x8*)(&Ah[p][ro + kc * 32 + q * 8]);
                a0 = __builtin_amdgcn_mfma_f32_16x16x32_bf16(wregH[0][kc], bh, a0, 0, 0, 0);
                a1 = __builtin_amdgcn_mfma_f32_16x16x32_bf16(wregH[1][kc], bh, a1, 0, 0, 0);
                a2 = __builtin_amdgcn_mfma_f32_16x16x32_bf16(wregH[2][kc], bh, a2, 0, 0, 0);
                if (hist)
                    a3 = __builtin_amdgcn_mfma_f32_16x16x32_bf16(wregH[3][kc], bh, a3, 0, 0, 0);
            }
#if XK16
            bf16x4 bx;
            if (hist) {
                unsigned short pb = phist_s[t * NN + row];
                bf16x4 z = {0,0,0,0};
                bx = z;
                if (q == 0) bx[0] = (short)pb;
                if (q == 2) { bx[0] = (short)corr0; bx[3] = (short)0x3F80; }
            } else {
                const unsigned short* bxp = (q < 2) ? (AxFS + row * 8 + q * 4)
                                          : (q == 2) ? (AxR + row * 8) : zero16;
                bx = *(const bf16x4*)bxp;
            }
            a0 = __builtin_amdgcn_mfma_f32_16x16x16bf16_1k(wregX[0], bx, a0, 0, 0, 0);
            a1 = __builtin_amdgcn_mfma_f32_16x16x16bf16_1k(wregX[1], bx, a1, 0, 0, 0);
            a2 = __builtin_amdgcn_mfma_f32_16x16x16bf16_1k(wregX[2], bx, a2, 0, 0, 0);
            a3 = __builtin_amdgcn_mfma_f32_16x16x16bf16_1k(wregX[3], bx, a3, 0, 0, 0);
#else
            bf16x8 bx;
            if (hist) {
                unsigned short pb = phist_s[t * NN + row];
                bf16x8 z = {0,0,0,0,0,0,0,0};
                bx = z;
                if (q == 0) bx[0] = (short)pb;
                if (q == 1) { bx[0] = (short)corr0; bx[3] = (short)0x3F80; }
            } else {
                const unsigned short* bxp = (q == 0) ? (AxFS + row * 8)
                                          : (q == 1) ? (AxR + row * 8) : zero16;
                bx = *(const bf16x8*)bxp;
            }
            a0 = __builtin_amdgcn_mfma_f32_16x16x32_bf16(wregX[0], bx, a0, 0, 0, 0);
            a1 = __builtin_amdgcn_mfma_f32_16x16x32_bf16(wregX[1], bx, a1, 0, 0, 0);
            a2 = __builtin_amdgcn_mfma_f32_16x16x32_bf16(wregX[2], bx, a2, 0, 0, 0);
            a3 = __builtin_amdgcn_mfma_f32_16x16x32_bf16(wregX[3], bx, a3, 0, 0, 0);
#endif

            // h_old readback (same bf16 this wave wrote last step)
            u32x2 hold = *(const u32x2*)&Ah[p][ro + cg * 16 + q * 4];

            float hn[4];
            #pragma unroll
            for (int rg = 0; rg < 4; ++rg) {
                unsigned hu = hold[rg >> 1];
                float ho = ((rg & 1) == 0) ? __uint_as_float(hu << 16)
                                           : __uint_as_float(hu & 0xffff0000u);
                // a0,a1 prescaled by log2e; a2,a3 by 2*log2e (biases folded)
                float rr = __builtin_amdgcn_rcpf(1.0f + EXP2(-a0[rg]));
                float zz = __builtin_amdgcn_rcpf(1.0f + EXP2(-a1[rg]));
                float wv = fmaf(rr, a2[rg], a3[rg]);
                unsigned sg = __float_as_uint(wv) & 0x80000000u;
                float e = EXP2(-fabsf(wv));
                float tv = (1.0f - e) * __builtin_amdgcn_rcpf(1.0f + e);
                tv = __uint_as_float(__float_as_uint(tv) ^ sg);
                hn[rg] = fmaf(zz, ho - tv, tv);
            }
            u32x2 pk;
            pk[0] = pkbf(hn[0], hn[1]);
            pk[1] = pkbf(hn[2], hn[3]);
            *(u32x2*)&Ah[p ^ 1][ro + cg * 16 + q * 4] = pk;
            if (dofc) {
                // fc partial (fp32): this lane's 4 cols, reduce over q
                float pf = hn[0] * fw.x + hn[1] * fw.y + hn[2] * fw.z + hn[3] * fw.w;
                pf += __shfl_xor(pf, 16);
                pf += __shfl_xor(pf, 32);
                if (q == 0) red_s[row * 9 + cg] = pf;        // stride 9: conflict-free
            }
        }
        __syncthreads();

        // ========== phase 3 (only t >= TH-1): xn reduce + dx rebuild =======
        if (dofc) {
            if (tid < NN) {
                float xn = fcls_f[128];
                #pragma unroll
                for (int c = 0; c < 8; ++c) xn += red_s[tid * 9 + c];
                float dv = 0.f;
                if (t2 >= TH && t2 < TH + TF)
                    dv = *(const float*)(stg[p ^ 1] + OFF_DINV + tid * 4);
                dx_s[tid] = make_float2(dv, xn);
                AxR[tid * 8 + 0] = f2bf(xn);
                if (t >= TH) pred[((long)bb * TF + (t - TH)) * NN + tid] = xn;
            }
            __syncthreads();
        }

        if (t == TH - 1)
            load_w(WaF, fcow, fcob, false);
        p ^= 1;
    }
}

extern "C" void kernel_launch(void* const* d_in, const int* in_sizes, int n_in,
                              void* d_out, int out_size, void* d_ws, size_t ws_size,
                              hipStream_t stream) {
    const float* feature = (const float*)d_in[0];
    const float* pm25    = (const float*)d_in[1];
    const float* adj     = (const float*)d_in[2];
    const float* angles  = (const float*)d_in[3];
    const float* W_ih_h  = (const float*)d_in[4];
    const float* W_hh_h  = (const float*)d_in[5];
    const float* b_ih_h  = (const float*)d_in[6];
    const float* b_hh_h  = (const float*)d_in[7];
    const float* fch_w   = (const float*)d_in[8];
    const float* fch_b   = (const float*)d_in[9];
    const float* cw0     = (const float*)d_in[10];
    const float* cw1     = (const float*)d_in[11];
    const float* cbb     = (const float*)d_in[12];
    const float* W_ih    = (const float*)d_in[13];
    const float* W_hh    = (const float*)d_in[14];
    const float* b_ih    = (const float*)d_in[15];
    const float* b_hh    = (const float*)d_in[16];
    const float* fco_w   = (const float*)d_in[17];
    const float* fco_b   = (const float*)d_in[18];
    float* pred = (float*)d_out;

    char* ws = (char*)d_ws;
    size_t off = 0;
    unsigned short* WaH   = (unsigned short*)(ws + off); off += (size_t)NG2 * KA * 2;  //   204,800
    unsigned short* WaF   = (unsigned short*)(ws + off); off += (size_t)NG2 * KA * 2;
    float4*         edges = (float4*)(ws + off);         off += (size_t)NN * NN * 16;  //   541,696
    int*            cnt   = (int*)(ws + off);            off += 16;
    unsigned short* phist = (unsigned short*)(ws + off); off += (size_t)BB * TH * NN * 2; // 2,260,992
    char*           xrec  = (char*)(ws + off);
    off += (size_t)BB * TF * REC_F;                                                    // 54,263,808

    hipMemsetAsync(cnt, 0, 16, stream);
    prep_weights<<<(NG2 * KA + 255) / 256, 256, 0, stream>>>(
        W_hh_h, W_ih_h, W_hh, W_ih, b_ih_h, b_hh_h, b_ih, b_hh, fch_w, fch_b,
        WaH, WaF);
    prep_edges<<<(NN * NN + 255) / 256, 256, 0, stream>>>(angles, adj, edges, cnt);
    prep_graph<<<BB * (TH + TF), 256, 0, stream>>>(
        feature, pm25, edges, cnt, cw0, cw1, cbb, xrec, phist);

    fused_dgc<<<BB, NT, 0, stream>>>(
        WaH, WaF, fch_w, fch_b, fco_w, fco_b, cw0, cw1, xrec, phist, pred);
}

// Round 6
// 619.313 us; speedup vs baseline: 1.2406x; 1.0415x over previous
//
#include <hip/hip_runtime.h>
#include <hip/hip_bf16.h>
#include <math.h>

#define BB 256
#define NN 184
#define HH 128
#define FF 8
#define TH 24
#define TF 24
#define KA 160       // augmented K (128 h + x block + pad; k=139 = bias col)
#define NG2 640      // 5 gate-parts x 128 (R, Z, NH, NX, NXH)
#define RPAD 192     // padded row count (12 tiles of 16)
#define STRH 136     // Ah row stride (elems)
#define NT 1024      // 16 waves, 4/SIMD
#define NW3 552      // mask words per (b,t)
#define LOG2E 1.44269504088896f

// per-(b,fore-t) staging record, 16B-granular, layout mirrored in LDS:
//   [mask 552*8 = 4416][dinv 184*4 = 736][G 184*4 = 736][AxF 184*16 = 2944] = 8832
#define REC_F 8832
#define OFF_DINV 4416
#define OFF_G 5152
#define OFF_AXF 5888

typedef __attribute__((ext_vector_type(8))) short bf16x8;
typedef __attribute__((ext_vector_type(4))) short bf16x4;
typedef __attribute__((ext_vector_type(4))) float f32x4;
typedef __attribute__((ext_vector_type(2))) unsigned u32x2;

#if __has_builtin(__builtin_amdgcn_mfma_f32_16x16x16bf16_1k)
#define XK16 1
#else
#define XK16 0
#endif

#if __has_builtin(__builtin_amdgcn_exp2f)
#define EXP2(x) __builtin_amdgcn_exp2f(x)
#else
#define EXP2(x) exp2f(x)
#endif

__device__ __forceinline__ unsigned short f2bf(float f) {
    unsigned u = __float_as_uint(f);
    u += 0x7fffu + ((u >> 16) & 1u);
    return (unsigned short)(u >> 16);
}
__device__ __forceinline__ unsigned pkbf(float a, float b) {
    __hip_bfloat162 h = __float22bfloat162_rn(make_float2(a, b));
    return *reinterpret_cast<unsigned*>(&h);
}
__device__ __forceinline__ void gload16(const void* src, void* dst) {
    __builtin_amdgcn_global_load_lds(
        (const __attribute__((address_space(1))) unsigned int*)src,
        (__attribute__((address_space(3))) unsigned int*)dst, 16, 0, 0);
}

// ---------------------------------------------------------------------------
// Augmented bf16 weights Wa[640][160] (R, Z, NH, NX, NXH), PRESCALED:
//   R,Z rows * log2e ; NH,NX,NXH rows * 2*log2e.
// HIST (WaH) xn-FOLDING: xn_t = fcw.h_t + fcb is linear in h ->
//   R,Z h-parts get + W_xn (x) fcw (rank-1), biases get + W_xn*fcb; part 4
//   (NXH) is the n-gate's xn rank-1 h-part (hist only).
// X-block slots (k-128): 0..7 = features (hist: slot0 = p), 8 = xn (fore;
// hist: t=0 correction -fcb), 9 = g, 11 = bias (pairs with const-1).
// ---------------------------------------------------------------------------
__global__ void prep_weights(const float* __restrict__ WhhH, const float* __restrict__ WihH,
                             const float* __restrict__ WhhF, const float* __restrict__ WihF,
                             const float* __restrict__ bihH, const float* __restrict__ bhhH,
                             const float* __restrict__ bihF, const float* __restrict__ bhhF,
                             const float* __restrict__ fchw, const float* __restrict__ fchb,
                             unsigned short* __restrict__ WaH, unsigned short* __restrict__ WaF) {
    int idx = blockIdx.x * 256 + threadIdx.x;
    if (idx >= NG2 * KA) return;
    int jp = idx / KA, k = idx % KA;
    int j = jp & 127, part = jp >> 7;
    float vh = 0.f, vf = 0.f;
    if (part <= 1) {              // R, Z
        int row = part * 128 + j;
        if (k < 128) {
            vh = WhhH[row * 128 + k] + WihH[row * 2 + 0] * fchw[k];   // xn fold
            vf = WhhF[row * 128 + k];
        } else {
            int s = k - 128;
            if (s == 0)  vh = WihH[row * 2 + 1];                      // p
            if (s < 8)   vf = WihF[row * 10 + (s + 1)];
            if (s == 8)  { vh = WihH[row * 2 + 0]; vf = WihF[row * 10 + 0]; }
            if (s == 9)  vf = WihF[row * 10 + 9];
            if (s == 11) {
                vh = bihH[row] + bhhH[row] + WihH[row * 2 + 0] * fchb[0];
                vf = bihF[row] + bhhF[row];
            }
        }
    } else if (part == 2) {       // NH: h part of n-gate + bhh at bias col
        if (k < 128) { vh = WhhH[(256 + j) * 128 + k]; vf = WhhF[(256 + j) * 128 + k]; }
        else if (k == 139) { vh = bhhH[256 + j]; vf = bhhF[256 + j]; }
    } else if (part == 3) {       // NX: x part of n-gate | bih@139
        if (k >= 128) {
            int s = k - 128;
            if (s == 0)  vh = WihH[(256 + j) * 2 + 1];
            if (s < 8)   vf = WihF[(256 + j) * 10 + (s + 1)];
            if (s == 8)  { vh = WihH[(256 + j) * 2 + 0]; vf = WihF[(256 + j) * 10 + 0]; }
            if (s == 9)  vf = WihF[(256 + j) * 10 + 9];
            if (s == 11) {
                vh = bihH[256 + j] + WihH[(256 + j) * 2 + 0] * fchb[0];
                vf = bihF[256 + j];
            }
        }
    } else {                      // NXH: rank-1 W_xn(n) (x) fcw, hist only
        if (k < 128) vh = WihH[(256 + j) * 2 + 0] * fchw[k];
    }
    float sc = (part <= 1) ? LOG2E : 2.0f * LOG2E;
    WaH[idx] = f2bf(vh * sc);
    WaF[idx] = f2bf(vf * sc);
}

// ---------------------------------------------------------------------------
// Sparse edge list over adj: rec = (c1, c2, i, j) as float4.
// ---------------------------------------------------------------------------
__global__ void prep_edges(const float* __restrict__ angles, const float* __restrict__ adj,
                           float4* __restrict__ edges, int* __restrict__ cnt) {
    int idx = blockIdx.x * 256 + threadIdx.x;
    if (idx < NN * NN && adj[idx] > 0.f) {
        float a = angles[idx];
        int pos = atomicAdd(cnt, 1);
        float4 r;
        r.x = cosf(a);
        r.y = cosf(a - 1.57079632679489662f);
        r.z = __int_as_float(idx / NN);   // i (source)
        r.w = __int_as_float(idx % NN);   // j (dest)
        edges[pos] = r;
    }
}

// ---------------------------------------------------------------------------
// Flat bf16 cast of pm25 (same memory order) -> phist.
// ---------------------------------------------------------------------------
__global__ void prep_hist(const float* __restrict__ pm25, unsigned short* __restrict__ phist) {
    int idx = blockIdx.x * 256 + threadIdx.x;
    if (idx < BB * TH * NN) phist[idx] = f2bf(pm25[idx]);
}

// ---------------------------------------------------------------------------
// Fore-record builder: one block per (batch, fore step): bitmask, dinv, G,
// AxF (word-parallel gather).
// ---------------------------------------------------------------------------
__global__ __launch_bounds__(256) void prep_graph(
    const float* __restrict__ feature,
    const float4* __restrict__ edges, const int* __restrict__ ecnt,
    const float* __restrict__ cw0, const float* __restrict__ cw1,
    const float* __restrict__ cbb, char* __restrict__ xrec)
{
    const int bt = blockIdx.x;
    const int b = bt / TF, tf = bt % TF;
    const int tt = TH + tf;
    const int tid = threadIdx.x;

    char* rec = xrec + ((long)b * TF + tf) * REC_F;

    __shared__ float f8[NN * FF];                   //  5,888 B
    __shared__ unsigned long long mT[NN][3];        //  4,416 B
    __shared__ int dg[NN];                          //    736 B
    __shared__ float di[NN];                        //    736 B
    __shared__ float red[NW3][8];                   // 17,664 B

    const float4* fb4 = (const float4*)(feature + ((long)b * (TH + TF) + tt) * (NN * FF));
    for (int i = tid; i < (NN * FF) / 4; i += 256) ((float4*)f8)[i] = fb4[i];
    for (int i = tid; i < NN * 3; i += 256) ((unsigned long long*)mT)[i] = 0ull;
    for (int i = tid; i < NN; i += 256) dg[i] = 0;
    __syncthreads();
    const int nE = *ecnt;
    for (int e = tid; e < nE; e += 256) {
        float4 r = edges[e];
        int ii = __float_as_int(r.z), jj = __float_as_int(r.w);
        if (f8[ii * FF] * r.x + f8[ii * FF + 1] * r.y >= 0.5f) {
            atomicAdd(&dg[ii], 1);
            atomicOr(&mT[jj][ii >> 6], 1ull << (ii & 63));
        }
    }
    __syncthreads();
    if (tid < NN) di[tid] = (dg[tid] > 0) ? rsqrtf((float)dg[tid]) : 0.f;
    __syncthreads();
    unsigned long long* mr = (unsigned long long*)rec;
    for (int i = tid; i < NW3; i += 256) mr[i] = ((const unsigned long long*)mT)[i];
    for (int task = tid; task < NW3; task += 256) {
        int j = task / 3, wd = task - j * 3;
        unsigned long long m = mT[j][wd];
        float acc[8];
        #pragma unroll
        for (int c = 0; c < 8; ++c) acc[c] = 0.f;
        while (m) {
            int bp = __ffsll(m) - 1; m &= m - 1;
            int i = wd * 64 + bp;
            float d = di[i];
            #pragma unroll
            for (int c = 0; c < 8; ++c) acc[c] += d * f8[i * FF + c];
        }
        #pragma unroll
        for (int c = 0; c < 8; ++c) red[task][c] = acc[c];
    }
    __syncthreads();
    if (tid < NN) {
        int j = tid;
        float dj = di[j];
        float hzj = (dj > 0.f) ? 0.f : -1.f;
        float G = cbb[0];
        #pragma unroll
        for (int c = 0; c < 8; ++c) {
            float accc = red[j * 3 + 0][c] + red[j * 3 + 1][c] + red[j * 3 + 2][c];
            float xv = f8[j * FF + c];
            float y = -dj * accc + hzj * xv;
            G += xv * cw0[c + 1] + y * cw1[c + 1];
        }
        ((float*)(rec + OFF_DINV))[j] = dj;
        ((float*)(rec + OFF_G))[j] = G;
        unsigned short* ax = (unsigned short*)(rec + OFF_AXF) + j * 8;
        #pragma unroll
        for (int c = 0; c < 8; ++c) ax[c] = f2bf(f8[j * FF + c]);
    }
}

// ---------------------------------------------------------------------------
// Persistent fused kernel, 2 barriers per fore step (1 per hist step):
//   fore t: [cheb(t): gather on xnraw(t-1) + finalize g/xn/pred(t-1) + zero
//            other xnraw buf | bar]
//           [stage(t+1) + GEMM + epilogue w/ fc -> atomicAdd xnraw(t&1) | bar]
//   hist t: [GEMM(+fc at TH-1) | bar]
// Gather algebra: sum di*xn = sum di*raw + fcb*sum di  (raw = fc dot, no
// bias), so epilogue can publish RAW sums via ds atomics and the bias folds
// into the gather finalize -- no xn-materialization phase needed.
// ---------------------------------------------------------------------------
__global__ __launch_bounds__(NT, 4) void fused_dgc(
    const unsigned short* __restrict__ WaH,
    const unsigned short* __restrict__ WaF,
    const float* __restrict__ fchw, const float* __restrict__ fchb,
    const float* __restrict__ fcow, const float* __restrict__ fcob,
    const float* __restrict__ cw0, const float* __restrict__ cw1,
    const char* __restrict__ xrec, const unsigned short* __restrict__ phist,
    float* __restrict__ pred)
{
    __shared__ unsigned short Ah[2][RPAD * STRH];   // 104,448 B
    __shared__ unsigned short AxR[RPAD * 8];        //   3,072 B (xn, g, -, 1.0, 0..)
    __shared__ __align__(16) char stg[2][8960];     //  17,920 B
    __shared__ float xnraw[2][RPAD];                //   1,536 B (raw fc sums, dbuf)
    __shared__ float fcls_f[132];                   //     528 B (fc w fp32 + bias@128)
    __shared__ unsigned short zero16[8];            //      16 B
    __shared__ __align__(16) unsigned short phist_s[TH * NN + 16];  // 8,864 B

    const int tid = threadIdx.x;
    const int bb = blockIdx.x;
    const int w = tid >> 6, lane = tid & 63, q = lane >> 4, lq = lane & 15;
    const int cg = w & 7, rh = w >> 3;

    for (int i = tid; i < RPAD * STRH; i += NT) Ah[0][i] = 0;
    for (int i = tid; i < RPAD * 8; i += NT)
        AxR[i] = ((i & 7) == 3) ? (unsigned short)0x3F80 : (unsigned short)0;
    if (tid < 8) zero16[tid] = 0;
    if (tid < RPAD) { xnraw[0][tid] = 0.f; xnraw[1][tid] = 0.f; }

    // ---- phase weights in registers ----
    bf16x8 wregH[4][4];   // parts: R,Z,NH (+NXH hist) : kc 0..3 (h part)
#if XK16
    bf16x4 wregX[4];      // R,Z,NH,NX : x block, K=16
#else
    bf16x8 wregX[4];      // K=32 fallback
#endif
    auto load_w = [&](const unsigned short* Wa, const float* fcw, const float* fcb, bool h4) {
        const int jcol = cg * 16 + lq;
        #pragma unroll
        for (int g = 0; g < 3; ++g)
            #pragma unroll
            for (int kc = 0; kc < 4; ++kc)
                wregH[g][kc] = *(const bf16x8*)(Wa + (long)(g * 128 + jcol) * KA + kc * 32 + q * 8);
        if (h4)
            #pragma unroll
            for (int kc = 0; kc < 4; ++kc)
                wregH[3][kc] = *(const bf16x8*)(Wa + (long)(4 * 128 + jcol) * KA + kc * 32 + q * 8);
        #pragma unroll
        for (int g = 0; g < 4; ++g)
#if XK16
            wregX[g] = *(const bf16x4*)(Wa + (long)(g * 128 + jcol) * KA + 128 + q * 4);
#else
            wregX[g] = *(const bf16x8*)(Wa + (long)(g * 128 + jcol) * KA + 128 + q * 8);
#endif
        if (tid < 132) fcls_f[tid] = (tid < 128) ? fcw[tid] : ((tid == 128) ? fcb[0] : 0.f);
    };
    load_w(WaH, fchw, fchb, true);

    // ---- stage the full pm25 block (8832 B, once) ----
    if (tid < NW3)
        gload16((const char*)phist + (long)bb * (TH * NN * 2) + tid * 16,
                (char*)phist_s + (tid & ~63) * 16);

    const float w00 = cw0[0], w10 = cw1[0];
    const float fcbH = fchb[0], fcbO = fcob[0];

    int p = 0;
    __syncthreads();       // init + phist visible

    for (int t = 0; t < TH + TF; ++t) {
        const bool hist = (t < TH);
        const bool dofc = (t >= TH - 1);
        const unsigned short* AxFS = (const unsigned short*)(stg[p] + OFF_AXF);

        // ====== cheb phase (fore): gather + finalize + pred + zero-buf =====
        if (!hist) {
            const unsigned long long* maskS = (const unsigned long long*)stg[p];
            const float* dinS = (const float*)(stg[p] + OFF_DINV);
            const float* GS = (const float*)(stg[p] + OFF_G);
            const float* xr = xnraw[(t - 1) & 1];
            const float fcbP = (t == TH) ? fcbH : fcbO;
            const int jg = tid >> 2, wd = tid & 3;
            if (jg < NN) {
                float acc = 0.f, accd = 0.f;
                if (wd < 3) {
                    unsigned long long m = maskS[jg * 3 + wd];
                    while (m) {
                        int bp = __ffsll(m) - 1; m &= m - 1;
                        int i = wd * 64 + bp;
                        float d = dinS[i];
                        acc = fmaf(d, xr[i], acc);
                        accd += d;
                    }
                }
                acc  += __shfl_xor(acc, 1);  acc  += __shfl_xor(acc, 2);
                accd += __shfl_xor(accd, 1); accd += __shfl_xor(accd, 2);
                if (wd == 0) {
                    float dj = dinS[jg];
                    float xnj = xr[jg] + fcbP;
                    float hzj = (dj > 0.f) ? 0.f : -1.f;
                    float sum = fmaf(fcbP, accd, acc);        // sum di*xn
                    float y0 = -dj * sum + hzj * xnj;
                    float pre = GS[jg] + xnj * w00 + y0 * w10;
                    float g = __builtin_amdgcn_rcpf(1.0f + EXP2(-LOG2E * pre));
                    AxR[jg * 8 + 1] = f2bf(g);
                    AxR[jg * 8 + 0] = f2bf(xnj);
                    if (t > TH) pred[((long)bb * TF + (t - 1 - TH)) * NN + jg] = xnj;
                }
            } else {
                int i = tid - 736;                            // 288 idle lanes
                if (i < RPAD) xnraw[t & 1][i] = 0.f;
            }
            __syncthreads();
        }

        // ====== issue t+1 fore-record staging (lands by post-GEMM bar) =====
        const int t2 = t + 1;
        if (t2 >= TH && t2 < TH + TF && tid < NW3)
            gload16(xrec + ((long)bb * TF + (t2 - TH)) * REC_F + tid * 16,
                    (char*)stg[p ^ 1] + (tid & ~63) * 16);

        // ========== GRU GEMM + epilogue (+ fc atomics if dofc) =============
        f32x4 fw = *(const f32x4*)&fcls_f[cg * 16 + q * 4];
        const unsigned short corr0 = (t == 0) ? f2bf(-fcbH) : (unsigned short)0;
        #pragma unroll
        for (int rl = 0; rl < 6; ++rl) {
            const int row = rh * 96 + rl * 16 + lq;
            const int ro = row * STRH;
            f32x4 a0 = {0.f,0.f,0.f,0.f}, a1 = {0.f,0.f,0.f,0.f}, a2 = {0.f,0.f,0.f,0.f};
            f32x4 a3 = {0.f,0.f,0.f,0.f};
            #pragma unroll
            for (int kc = 0; kc < 4; ++kc) {
                bf16x8 bh = *(const bf16x8*)(&Ah[p][ro + kc * 32 + q * 8]);
                a0 = __builtin_amdgcn_mfma_f32_16x16x32_bf16(wregH[0][kc], bh, a0, 0, 0, 0);
                a1 = __builtin_amdgcn_mfma_f32_16x16x32_bf16(wregH[1][kc], bh, a1, 0, 0, 0);
                a2 = __builtin_amdgcn_mfma_f32_16x16x32_bf16(wregH[2][kc], bh, a2, 0, 0, 0);
                if (hist)
                    a3 = __builtin_amdgcn_mfma_f32_16x16x32_bf16(wregH[3][kc], bh, a3, 0, 0, 0);
            }
#if XK16
            bf16x4 bx;
            if (hist) {
                unsigned short pb = phist_s[t * NN + row];
                bf16x4 z = {0,0,0,0};
                bx = z;
                if (q == 0) bx[0] = (short)pb;
                if (q == 2) { bx[0] = (short)corr0; bx[3] = (short)0x3F80; }
            } else {
                const unsigned short* bxp = (q < 2) ? (AxFS + row * 8 + q * 4)
                                          : (q == 2) ? (AxR + row * 8) : zero16;
                bx = *(const bf16x4*)bxp;
            }
            a0 = __builtin_amdgcn_mfma_f32_16x16x16bf16_1k(wregX[0], bx, a0, 0, 0, 0);
            a1 = __builtin_amdgcn_mfma_f32_16x16x16bf16_1k(wregX[1], bx, a1, 0, 0, 0);
            a2 = __builtin_amdgcn_mfma_f32_16x16x16bf16_1k(wregX[2], bx, a2, 0, 0, 0);
            a3 = __builtin_amdgcn_mfma_f32_16x16x16bf16_1k(wregX[3], bx, a3, 0, 0, 0);
#else
            bf16x8 bx;
            if (hist) {
                unsigned short pb = phist_s[t * NN + row];
                bf16x8 z = {0,0,0,0,0,0,0,0};
                bx = z;
                if (q == 0) bx[0] = (short)pb;
                if (q == 1) { bx[0] = (short)corr0; bx[3] = (short)0x3F80; }
            } else {
                const unsigned short* bxp = (q == 0) ? (AxFS + row * 8)
                                          : (q == 1) ? (AxR + row * 8) : zero16;
                bx = *(const bf16x8*)bxp;
            }
            a0 = __builtin_amdgcn_mfma_f32_16x16x32_bf16(wregX[0], bx, a0, 0, 0, 0);
            a1 = __builtin_amdgcn_mfma_f32_16x16x32_bf16(wregX[1], bx, a1, 0, 0, 0);
            a2 = __builtin_amdgcn_mfma_f32_16x16x32_bf16(wregX[2], bx, a2, 0, 0, 0);
            a3 = __builtin_amdgcn_mfma_f32_16x16x32_bf16(wregX[3], bx, a3, 0, 0, 0);
#endif

            // h_old readback (same bf16 this wave wrote last step)
            u32x2 hold = *(const u32x2*)&Ah[p][ro + cg * 16 + q * 4];

            float hn[4];
            #pragma unroll
            for (int rg = 0; rg < 4; ++rg) {
                unsigned hu = hold[rg >> 1];
                float ho = ((rg & 1) == 0) ? __uint_as_float(hu << 16)
                                           : __uint_as_float(hu & 0xffff0000u);
                // a0,a1 prescaled by log2e; a2,a3 by 2*log2e (biases folded)
                float rr = __builtin_amdgcn_rcpf(1.0f + EXP2(-a0[rg]));
                float zz = __builtin_amdgcn_rcpf(1.0f + EXP2(-a1[rg]));
                float wv = fmaf(rr, a2[rg], a3[rg]);
                unsigned sg = __float_as_uint(wv) & 0x80000000u;
                float e = EXP2(-fabsf(wv));
                float tv = (1.0f - e) * __builtin_amdgcn_rcpf(1.0f + e);
                tv = __uint_as_float(__float_as_uint(tv) ^ sg);
                hn[rg] = fmaf(zz, ho - tv, tv);
            }
            u32x2 pk;
            pk[0] = pkbf(hn[0], hn[1]);
            pk[1] = pkbf(hn[2], hn[3]);
            *(u32x2*)&Ah[p ^ 1][ro + cg * 16 + q * 4] = pk;
            if (dofc) {
                // fc partial (fp32, raw): reduce over q, publish via ds atomic
                float pf = hn[0] * fw.x + hn[1] * fw.y + hn[2] * fw.z + hn[3] * fw.w;
                pf += __shfl_xor(pf, 16);
                pf += __shfl_xor(pf, 32);
                if (q == 0) atomicAdd(&xnraw[t & 1][row], pf);
            }
        }
        __syncthreads();

        if (t == TH - 1)
            load_w(WaF, fcow, fcob, false);
        p ^= 1;
    }

    // ---- tail: last prediction (xn of final fore step) ----
    if (tid < NN)
        pred[((long)bb * TF + (TF - 1)) * NN + tid] =
            xnraw[(TH + TF - 1) & 1][tid] + fcbO;
}

extern "C" void kernel_launch(void* const* d_in, const int* in_sizes, int n_in,
                              void* d_out, int out_size, void* d_ws, size_t ws_size,
                              hipStream_t stream) {
    const float* feature = (const float*)d_in[0];
    const float* pm25    = (const float*)d_in[1];
    const float* adj     = (const float*)d_in[2];
    const float* angles  = (const float*)d_in[3];
    const float* W_ih_h  = (const float*)d_in[4];
    const float* W_hh_h  = (const float*)d_in[5];
    const float* b_ih_h  = (const float*)d_in[6];
    const float* b_hh_h  = (const float*)d_in[7];
    const float* fch_w   = (const float*)d_in[8];
    const float* fch_b   = (const float*)d_in[9];
    const float* cw0     = (const float*)d_in[10];
    const float* cw1     = (const float*)d_in[11];
    const float* cbb     = (const float*)d_in[12];
    const float* W_ih    = (const float*)d_in[13];
    const float* W_hh    = (const float*)d_in[14];
    const float* b_ih    = (const float*)d_in[15];
    const float* b_hh    = (const float*)d_in[16];
    const float* fco_w   = (const float*)d_in[17];
    const float* fco_b   = (const float*)d_in[18];
    float* pred = (float*)d_out;

    char* ws = (char*)d_ws;
    size_t off = 0;
    unsigned short* WaH   = (unsigned short*)(ws + off); off += (size_t)NG2 * KA * 2;  //   204,800
    unsigned short* WaF   = (unsigned short*)(ws + off); off += (size_t)NG2 * KA * 2;
    float4*         edges = (float4*)(ws + off);         off += (size_t)NN * NN * 16;  //   541,696
    int*            cnt   = (int*)(ws + off);            off += 16;
    unsigned short* phist = (unsigned short*)(ws + off); off += (size_t)BB * TH * NN * 2; // 2,260,992
    char*           xrec  = (char*)(ws + off);
    off += (size_t)BB * TF * REC_F;                                                    // 54,263,808

    hipMemsetAsync(cnt, 0, 16, stream);
    prep_weights<<<(NG2 * KA + 255) / 256, 256, 0, stream>>>(
        W_hh_h, W_ih_h, W_hh, W_ih, b_ih_h, b_hh_h, b_ih, b_hh, fch_w, fch_b,
        WaH, WaF);
    prep_edges<<<(NN * NN + 255) / 256, 256, 0, stream>>>(angles, adj, edges, cnt);
    prep_hist<<<(BB * TH * NN + 255) / 256, 256, 0, stream>>>(pm25, phist);
    prep_graph<<<BB * TF, 256, 0, stream>>>(
        feature, edges, cnt, cw0, cw1, cbb, xrec);

    fused_dgc<<<BB, NT, 0, stream>>>(
        WaH, WaF, fch_w, fch_b, fco_w, fco_b, cw0, cw1, xrec, phist, pred);
}

// Round 7
// 573.122 us; speedup vs baseline: 1.3406x; 1.0806x over previous
//
#include <hip/hip_runtime.h>
#include <hip/hip_bf16.h>
#include <math.h>

#define BB 256
#define NN 184
#define HH 128
#define FF 8
#define TH 24
#define TF 24
#define KA 160       // augmented K (128 h + x block + pad; k=139 = bias col)
#define NG2 640      // 5 gate-parts x 128 (R, Z, NH, NX, NXH)
#define RPAD 192     // padded row count (12 tiles of 16)
#define STRH 136     // Ah row stride (elems)
#define NT 1024      // 16 waves, 4/SIMD
#define NW3 552      // mask words per (b,t)
#define LOG2E 1.44269504088896f

// per-(b,fore-t) staging record, 16B-granular, layout mirrored in LDS:
//   [mask 552*8 = 4416][dinv 184*4 = 736][G 184*4 = 736][AxF 184*16 = 2944] = 8832
#define REC_F 8832
#define OFF_DINV 4416
#define OFF_G 5152
#define OFF_AXF 5888

typedef __attribute__((ext_vector_type(8))) short bf16x8;
typedef __attribute__((ext_vector_type(4))) short bf16x4;
typedef __attribute__((ext_vector_type(4))) float f32x4;
typedef __attribute__((ext_vector_type(2))) unsigned u32x2;

#if __has_builtin(__builtin_amdgcn_mfma_f32_16x16x16bf16_1k)
#define XK16 1
#else
#define XK16 0
#endif

#if __has_builtin(__builtin_amdgcn_exp2f)
#define EXP2(x) __builtin_amdgcn_exp2f(x)
#else
#define EXP2(x) exp2f(x)
#endif

__device__ __forceinline__ unsigned short f2bf(float f) {
    unsigned u = __float_as_uint(f);
    u += 0x7fffu + ((u >> 16) & 1u);
    return (unsigned short)(u >> 16);
}
__device__ __forceinline__ unsigned pkbf(float a, float b) {
    __hip_bfloat162 h = __float22bfloat162_rn(make_float2(a, b));
    return *reinterpret_cast<unsigned*>(&h);
}
__device__ __forceinline__ void gload16(const void* src, void* dst) {
    __builtin_amdgcn_global_load_lds(
        (const __attribute__((address_space(1))) unsigned int*)src,
        (__attribute__((address_space(3))) unsigned int*)dst, 16, 0, 0);
}

// ---------------------------------------------------------------------------
// Augmented bf16 weights Wa[640][160] (R, Z, NH, NX, NXH), PRESCALED:
//   R,Z rows * log2e ; NH,NX,NXH rows * 2*log2e.
// HIST (WaH) xn-FOLDING: xn_t = fcw.h_t + fcb is linear in h ->
//   R,Z h-parts get + W_xn (x) fcw (rank-1), biases get + W_xn*fcb; part 4
//   (NXH) is the n-gate's xn rank-1 h-part (hist only).
// X-block slots (k-128): 0..7 = features (hist: slot0 = p), 8 = xn (fore;
// hist: t=0 correction -fcb), 9 = g, 11 = bias (pairs with const-1).
// ---------------------------------------------------------------------------
__global__ void prep_weights(const float* __restrict__ WhhH, const float* __restrict__ WihH,
                             const float* __restrict__ WhhF, const float* __restrict__ WihF,
                             const float* __restrict__ bihH, const float* __restrict__ bhhH,
                             const float* __restrict__ bihF, const float* __restrict__ bhhF,
                             const float* __restrict__ fchw, const float* __restrict__ fchb,
                             unsigned short* __restrict__ WaH, unsigned short* __restrict__ WaF) {
    int idx = blockIdx.x * 256 + threadIdx.x;
    if (idx >= NG2 * KA) return;
    int jp = idx / KA, k = idx % KA;
    int j = jp & 127, part = jp >> 7;
    float vh = 0.f, vf = 0.f;
    if (part <= 1) {              // R, Z
        int row = part * 128 + j;
        if (k < 128) {
            vh = WhhH[row * 128 + k] + WihH[row * 2 + 0] * fchw[k];   // xn fold
            vf = WhhF[row * 128 + k];
        } else {
            int s = k - 128;
            if (s == 0)  vh = WihH[row * 2 + 1];                      // p
            if (s < 8)   vf = WihF[row * 10 + (s + 1)];
            if (s == 8)  { vh = WihH[row * 2 + 0]; vf = WihF[row * 10 + 0]; }
            if (s == 9)  vf = WihF[row * 10 + 9];
            if (s == 11) {
                vh = bihH[row] + bhhH[row] + WihH[row * 2 + 0] * fchb[0];
                vf = bihF[row] + bhhF[row];
            }
        }
    } else if (part == 2) {       // NH: h part of n-gate + bhh at bias col
        if (k < 128) { vh = WhhH[(256 + j) * 128 + k]; vf = WhhF[(256 + j) * 128 + k]; }
        else if (k == 139) { vh = bhhH[256 + j]; vf = bhhF[256 + j]; }
    } else if (part == 3) {       // NX: x part of n-gate | bih@139
        if (k >= 128) {
            int s = k - 128;
            if (s == 0)  vh = WihH[(256 + j) * 2 + 1];
            if (s < 8)   vf = WihF[(256 + j) * 10 + (s + 1)];
            if (s == 8)  { vh = WihH[(256 + j) * 2 + 0]; vf = WihF[(256 + j) * 10 + 0]; }
            if (s == 9)  vf = WihF[(256 + j) * 10 + 9];
            if (s == 11) {
                vh = bihH[256 + j] + WihH[(256 + j) * 2 + 0] * fchb[0];
                vf = bihF[256 + j];
            }
        }
    } else {                      // NXH: rank-1 W_xn(n) (x) fcw, hist only
        if (k < 128) vh = WihH[(256 + j) * 2 + 0] * fchw[k];
    }
    float sc = (part <= 1) ? LOG2E : 2.0f * LOG2E;
    WaH[idx] = f2bf(vh * sc);
    WaF[idx] = f2bf(vf * sc);
}

// ---------------------------------------------------------------------------
// Sparse edge list over adj: rec = (c1, c2, i, j) as float4.
// ---------------------------------------------------------------------------
__global__ void prep_edges(const float* __restrict__ angles, const float* __restrict__ adj,
                           float4* __restrict__ edges, int* __restrict__ cnt) {
    int idx = blockIdx.x * 256 + threadIdx.x;
    if (idx < NN * NN && adj[idx] > 0.f) {
        float a = angles[idx];
        int pos = atomicAdd(cnt, 1);
        float4 r;
        r.x = cosf(a);
        r.y = cosf(a - 1.57079632679489662f);
        r.z = __int_as_float(idx / NN);   // i (source)
        r.w = __int_as_float(idx % NN);   // j (dest)
        edges[pos] = r;
    }
}

// ---------------------------------------------------------------------------
// Flat bf16 cast of pm25 (same memory order) -> phist.
// ---------------------------------------------------------------------------
__global__ void prep_hist(const float* __restrict__ pm25, unsigned short* __restrict__ phist) {
    int idx = blockIdx.x * 256 + threadIdx.x;
    if (idx < BB * TH * NN) phist[idx] = f2bf(pm25[idx]);
}

// ---------------------------------------------------------------------------
// Fore-record builder: one block per (batch, fore step). SCALAR gather:
//   G_j = cb + S0_j + hz_j*S1_j - d_j * sum_{i in M(j)} s_i,
//   s_i = d_i * (f_i . w1),  S0 = f_j . w0,  S1 = f_j . w1
// (exact reassociation of the 8-channel form; 1 LDS read + 1 add per bit).
// ---------------------------------------------------------------------------
__global__ __launch_bounds__(256) void prep_graph(
    const float* __restrict__ feature,
    const float4* __restrict__ edges, const int* __restrict__ ecnt,
    const float* __restrict__ cw0, const float* __restrict__ cw1,
    const float* __restrict__ cbb, char* __restrict__ xrec)
{
    const int bt = blockIdx.x;
    const int b = bt / TF, tf = bt % TF;
    const int tt = TH + tf;
    const int tid = threadIdx.x;

    char* rec = xrec + ((long)b * TF + tf) * REC_F;

    __shared__ float f8[NN * FF];                   //  5,888 B
    __shared__ unsigned long long mT[NN][3];        //  4,416 B
    __shared__ int dg[NN];                          //    736 B
    __shared__ float di[NN];                        //    736 B
    __shared__ float sI[NN];                        //    736 B
    __shared__ float red[NW3];                      //  2,208 B

    const float4* fb4 = (const float4*)(feature + ((long)b * (TH + TF) + tt) * (NN * FF));
    for (int i = tid; i < (NN * FF) / 4; i += 256) ((float4*)f8)[i] = fb4[i];
    for (int i = tid; i < NN * 3; i += 256) ((unsigned long long*)mT)[i] = 0ull;
    for (int i = tid; i < NN; i += 256) dg[i] = 0;
    __syncthreads();
    const int nE = *ecnt;
    for (int e = tid; e < nE; e += 256) {
        float4 r = edges[e];
        int ii = __float_as_int(r.z), jj = __float_as_int(r.w);
        if (f8[ii * FF] * r.x + f8[ii * FF + 1] * r.y >= 0.5f) {
            atomicAdd(&dg[ii], 1);
            atomicOr(&mT[jj][ii >> 6], 1ull << (ii & 63));
        }
    }
    __syncthreads();
    if (tid < NN) {
        float d = (dg[tid] > 0) ? rsqrtf((float)dg[tid]) : 0.f;
        di[tid] = d;
        float s = 0.f;
        #pragma unroll
        for (int c = 0; c < 8; ++c) s = fmaf(f8[tid * FF + c], cw1[c + 1], s);
        sI[tid] = d * s;
    }
    __syncthreads();
    unsigned long long* mr = (unsigned long long*)rec;
    for (int i = tid; i < NW3; i += 256) mr[i] = ((const unsigned long long*)mT)[i];
    for (int task = tid; task < NW3; task += 256) {
        int j = task / 3, wd = task - j * 3;
        unsigned long long m = mT[j][wd];
        float acc = 0.f;
        while (m) {
            int bp = __ffsll(m) - 1; m &= m - 1;
            acc += sI[wd * 64 + bp];
        }
        red[task] = acc;
    }
    __syncthreads();
    if (tid < NN) {
        int j = tid;
        float dj = di[j];
        float hzj = (dj > 0.f) ? 0.f : -1.f;
        float S0 = 0.f, S1 = 0.f;
        #pragma unroll
        for (int c = 0; c < 8; ++c) {
            float xv = f8[j * FF + c];
            S0 = fmaf(xv, cw0[c + 1], S0);
            S1 = fmaf(xv, cw1[c + 1], S1);
        }
        float G = cbb[0] + S0 + hzj * S1
                - dj * (red[j * 3 + 0] + red[j * 3 + 1] + red[j * 3 + 2]);
        ((float*)(rec + OFF_DINV))[j] = dj;
        ((float*)(rec + OFF_G))[j] = G;
        unsigned short* ax = (unsigned short*)(rec + OFF_AXF) + j * 8;
        #pragma unroll
        for (int c = 0; c < 8; ++c) ax[c] = f2bf(f8[j * FF + c]);
    }
}

// ---------------------------------------------------------------------------
// Persistent fused kernel, 2 barriers per fore step (1 per hist step):
//   fore t: [cheb(t): gather on xnraw(t-1) + finalize g/xn/pred(t-1) + zero
//            other xnraw buf | bar]
//           [stage(t+1) + GEMM + epilogue w/ fc -> atomicAdd xnraw(t&1) | bar]
//   hist t: [GEMM(+fc at TH-1) | bar]
// Issue diet (r7): zero-C MFMA chains (no per-tile acc zero-init movs);
// tanh via sigmoid-form (no sign-trick: -4 VALU ops/site, same trans count).
// ---------------------------------------------------------------------------
__global__ __launch_bounds__(NT, 4) void fused_dgc(
    const unsigned short* __restrict__ WaH,
    const unsigned short* __restrict__ WaF,
    const float* __restrict__ fchw, const float* __restrict__ fchb,
    const float* __restrict__ fcow, const float* __restrict__ fcob,
    const float* __restrict__ cw0, const float* __restrict__ cw1,
    const char* __restrict__ xrec, const unsigned short* __restrict__ phist,
    float* __restrict__ pred)
{
    __shared__ unsigned short Ah[2][RPAD * STRH];   // 104,448 B
    __shared__ unsigned short AxR[RPAD * 8];        //   3,072 B (xn, g, -, 1.0, 0..)
    __shared__ __align__(16) char stg[2][8960];     //  17,920 B
    __shared__ float xnraw[2][RPAD];                //   1,536 B (raw fc sums, dbuf)
    __shared__ float fcls_f[132];                   //     528 B (fc w fp32 + bias@128)
    __shared__ unsigned short zero16[8];            //      16 B
    __shared__ __align__(16) unsigned short phist_s[TH * NN + 16];  // 8,864 B

    const int tid = threadIdx.x;
    const int bb = blockIdx.x;
    const int w = tid >> 6, lane = tid & 63, q = lane >> 4, lq = lane & 15;
    const int cg = w & 7, rh = w >> 3;

    for (int i = tid; i < RPAD * STRH; i += NT) Ah[0][i] = 0;
    for (int i = tid; i < RPAD * 8; i += NT)
        AxR[i] = ((i & 7) == 3) ? (unsigned short)0x3F80 : (unsigned short)0;
    if (tid < 8) zero16[tid] = 0;
    if (tid < RPAD) { xnraw[0][tid] = 0.f; xnraw[1][tid] = 0.f; }

    // ---- phase weights in registers ----
    bf16x8 wregH[4][4];   // parts: R,Z,NH (+NXH hist) : kc 0..3 (h part)
#if XK16
    bf16x4 wregX[4];      // R,Z,NH,NX : x block, K=16
#else
    bf16x8 wregX[4];      // K=32 fallback
#endif
    auto load_w = [&](const unsigned short* Wa, const float* fcw, const float* fcb, bool h4) {
        const int jcol = cg * 16 + lq;
        #pragma unroll
        for (int g = 0; g < 3; ++g)
            #pragma unroll
            for (int kc = 0; kc < 4; ++kc)
                wregH[g][kc] = *(const bf16x8*)(Wa + (long)(g * 128 + jcol) * KA + kc * 32 + q * 8);
        if (h4)
            #pragma unroll
            for (int kc = 0; kc < 4; ++kc)
                wregH[3][kc] = *(const bf16x8*)(Wa + (long)(4 * 128 + jcol) * KA + kc * 32 + q * 8);
        #pragma unroll
        for (int g = 0; g < 4; ++g)
#if XK16
            wregX[g] = *(const bf16x4*)(Wa + (long)(g * 128 + jcol) * KA + 128 + q * 4);
#else
            wregX[g] = *(const bf16x8*)(Wa + (long)(g * 128 + jcol) * KA + 128 + q * 8);
#endif
        if (tid < 132) fcls_f[tid] = (tid < 128) ? fcw[tid] : ((tid == 128) ? fcb[0] : 0.f);
    };
    load_w(WaH, fchw, fchb, true);

    // ---- stage the full pm25 block (8832 B, once) ----
    if (tid < NW3)
        gload16((const char*)phist + (long)bb * (TH * NN * 2) + tid * 16,
                (char*)phist_s + (tid & ~63) * 16);

    const float w00 = cw0[0], w10 = cw1[0];
    const float fcbH = fchb[0], fcbO = fcob[0];
    const f32x4 zf = {0.f, 0.f, 0.f, 0.f};

    int p = 0;
    __syncthreads();       // init + phist visible

    for (int t = 0; t < TH + TF; ++t) {
        const bool hist = (t < TH);
        const bool dofc = (t >= TH - 1);
        const unsigned short* AxFS = (const unsigned short*)(stg[p] + OFF_AXF);

        // ====== cheb phase (fore): gather + finalize + pred + zero-buf =====
        if (!hist) {
            const unsigned long long* maskS = (const unsigned long long*)stg[p];
            const float* dinS = (const float*)(stg[p] + OFF_DINV);
            const float* GS = (const float*)(stg[p] + OFF_G);
            const float* xr = xnraw[(t - 1) & 1];
            const float fcbP = (t == TH) ? fcbH : fcbO;
            const int jg = tid >> 2, wd = tid & 3;
            if (jg < NN) {
                float acc = 0.f, accd = 0.f;
                if (wd < 3) {
                    unsigned long long m = maskS[jg * 3 + wd];
                    while (m) {
                        int bp = __ffsll(m) - 1; m &= m - 1;
                        int i = wd * 64 + bp;
                        float d = dinS[i];
                        acc = fmaf(d, xr[i], acc);
                        accd += d;
                    }
                }
                acc  += __shfl_xor(acc, 1);  acc  += __shfl_xor(acc, 2);
                accd += __shfl_xor(accd, 1); accd += __shfl_xor(accd, 2);
                if (wd == 0) {
                    float dj = dinS[jg];
                    float xnj = xr[jg] + fcbP;
                    float hzj = (dj > 0.f) ? 0.f : -1.f;
                    float sum = fmaf(fcbP, accd, acc);        // sum di*xn
                    float y0 = -dj * sum + hzj * xnj;
                    float pre = GS[jg] + xnj * w00 + y0 * w10;
                    float g = __builtin_amdgcn_rcpf(1.0f + EXP2(-LOG2E * pre));
                    AxR[jg * 8 + 1] = f2bf(g);
                    AxR[jg * 8 + 0] = f2bf(xnj);
                    if (t > TH) pred[((long)bb * TF + (t - 1 - TH)) * NN + jg] = xnj;
                }
            } else {
                int i = tid - 736;                            // 288 idle lanes
                if (i < RPAD) xnraw[t & 1][i] = 0.f;
            }
            __syncthreads();
        }

        // ====== issue t+1 fore-record staging (lands by post-GEMM bar) =====
        const int t2 = t + 1;
        if (t2 >= TH && t2 < TH + TF && tid < NW3)
            gload16(xrec + ((long)bb * TF + (t2 - TH)) * REC_F + tid * 16,
                    (char*)stg[p ^ 1] + (tid & ~63) * 16);

        // ========== GRU GEMM + epilogue (+ fc atomics if dofc) =============
        f32x4 fw = *(const f32x4*)&fcls_f[cg * 16 + q * 4];
        const unsigned short corr0 = (t == 0) ? f2bf(-fcbH) : (unsigned short)0;
        #pragma unroll
        for (int rl = 0; rl < 6; ++rl) {
            const int row = rh * 96 + rl * 16 + lq;
            const int ro = row * STRH;
            f32x4 a0, a1, a2, a3;
            {   // kc = 0: zero-C chains (no acc zero-init movs)
                bf16x8 bh = *(const bf16x8*)(&Ah[p][ro + q * 8]);
                a0 = __builtin_amdgcn_mfma_f32_16x16x32_bf16(wregH[0][0], bh, zf, 0, 0, 0);
                a1 = __builtin_amdgcn_mfma_f32_16x16x32_bf16(wregH[1][0], bh, zf, 0, 0, 0);
                a2 = __builtin_amdgcn_mfma_f32_16x16x32_bf16(wregH[2][0], bh, zf, 0, 0, 0);
                a3 = hist ? __builtin_amdgcn_mfma_f32_16x16x32_bf16(wregH[3][0], bh, zf, 0, 0, 0)
                          : zf;
            }
            #pragma unroll
            for (int kc = 1; kc < 4; ++kc) {
                bf16x8 bh = *(const bf16x8*)(&Ah[p][ro + kc * 32 + q * 8]);
                a0 = __builtin_amdgcn_mfma_f32_16x16x32_bf16(wregH[0][kc], bh, a0, 0, 0, 0);
                a1 = __builtin_amdgcn_mfma_f32_16x16x32_bf16(wregH[1][kc], bh, a1, 0, 0, 0);
                a2 = __builtin_amdgcn_mfma_f32_16x16x32_bf16(wregH[2][kc], bh, a2, 0, 0, 0);
                if (hist)
                    a3 = __builtin_amdgcn_mfma_f32_16x16x32_bf16(wregH[3][kc], bh, a3, 0, 0, 0);
            }
#if XK16
            bf16x4 bx;
            if (hist) {
                unsigned short pb = phist_s[t * NN + row];
                bf16x4 z = {0,0,0,0};
                bx = z;
                if (q == 0) bx[0] = (short)pb;
                if (q == 2) { bx[0] = (short)corr0; bx[3] = (short)0x3F80; }
            } else {
                const unsigned short* bxp = (q < 2) ? (AxFS + row * 8 + q * 4)
                                          : (q == 2) ? (AxR + row * 8) : zero16;
                bx = *(const bf16x4*)bxp;
            }
            a0 = __builtin_amdgcn_mfma_f32_16x16x16bf16_1k(wregX[0], bx, a0, 0, 0, 0);
            a1 = __builtin_amdgcn_mfma_f32_16x16x16bf16_1k(wregX[1], bx, a1, 0, 0, 0);
            a2 = __builtin_amdgcn_mfma_f32_16x16x16bf16_1k(wregX[2], bx, a2, 0, 0, 0);
            a3 = __builtin_amdgcn_mfma_f32_16x16x16bf16_1k(wregX[3], bx, a3, 0, 0, 0);
#else
            bf16x8 bx;
            if (hist) {
                unsigned short pb = phist_s[t * NN + row];
                bf16x8 z = {0,0,0,0,0,0,0,0};
                bx = z;
                if (q == 0) bx[0] = (short)pb;
                if (q == 1) { bx[0] = (short)corr0; bx[3] = (short)0x3F80; }
            } else {
                const unsigned short* bxp = (q == 0) ? (AxFS + row * 8)
                                          : (q == 1) ? (AxR + row * 8) : zero16;
                bx = *(const bf16x8*)bxp;
            }
            a0 = __builtin_amdgcn_mfma_f32_16x16x32_bf16(wregX[0], bx, a0, 0, 0, 0);
            a1 = __builtin_amdgcn_mfma_f32_16x16x32_bf16(wregX[1], bx, a1, 0, 0, 0);
            a2 = __builtin_amdgcn_mfma_f32_16x16x32_bf16(wregX[2], bx, a2, 0, 0, 0);
            a3 = __builtin_amdgcn_mfma_f32_16x16x32_bf16(wregX[3], bx, a3, 0, 0, 0);
#endif

            // h_old readback (same bf16 this wave wrote last step)
            u32x2 hold = *(const u32x2*)&Ah[p][ro + cg * 16 + q * 4];

            float hn[4];
            #pragma unroll
            for (int rg = 0; rg < 4; ++rg) {
                unsigned hu = hold[rg >> 1];
                float ho = ((rg & 1) == 0) ? __uint_as_float(hu << 16)
                                           : __uint_as_float(hu & 0xffff0000u);
                // a0,a1 prescaled by log2e; a2,a3 by 2*log2e (biases folded)
                float rr = __builtin_amdgcn_rcpf(1.0f + EXP2(-a0[rg]));
                float zz = __builtin_amdgcn_rcpf(1.0f + EXP2(-a1[rg]));
                float wv = fmaf(rr, a2[rg], a3[rg]);
                // tanh(v) = 2*sigmoid(2v) - 1 ; wv = 2*log2e*v
                float s2 = __builtin_amdgcn_rcpf(1.0f + EXP2(-wv));
                float tv = fmaf(2.0f, s2, -1.0f);
                hn[rg] = fmaf(zz, ho - tv, tv);
            }
            u32x2 pk;
            pk[0] = pkbf(hn[0], hn[1]);
            pk[1] = pkbf(hn[2], hn[3]);
            *(u32x2*)&Ah[p ^ 1][ro + cg * 16 + q * 4] = pk;
            if (dofc) {
                // fc partial (fp32, raw): reduce over q, publish via ds atomic
                float pf = hn[0] * fw.x + hn[1] * fw.y + hn[2] * fw.z + hn[3] * fw.w;
                pf += __shfl_xor(pf, 16);
                pf += __shfl_xor(pf, 32);
                if (q == 0) atomicAdd(&xnraw[t & 1][row], pf);
            }
        }
        __syncthreads();

        if (t == TH - 1)
            load_w(WaF, fcow, fcob, false);
        p ^= 1;
    }

    // ---- tail: last prediction (xn of final fore step) ----
    if (tid < NN)
        pred[((long)bb * TF + (TF - 1)) * NN + tid] =
            xnraw[(TH + TF - 1) & 1][tid] + fcbO;
}

extern "C" void kernel_launch(void* const* d_in, const int* in_sizes, int n_in,
                              void* d_out, int out_size, void* d_ws, size_t ws_size,
                              hipStream_t stream) {
    const float* feature = (const float*)d_in[0];
    const float* pm25    = (const float*)d_in[1];
    const float* adj     = (const float*)d_in[2];
    const float* angles  = (const float*)d_in[3];
    const float* W_ih_h  = (const float*)d_in[4];
    const float* W_hh_h  = (const float*)d_in[5];
    const float* b_ih_h  = (const float*)d_in[6];
    const float* b_hh_h  = (const float*)d_in[7];
    const float* fch_w   = (const float*)d_in[8];
    const float* fch_b   = (const float*)d_in[9];
    const float* cw0     = (const float*)d_in[10];
    const float* cw1     = (const float*)d_in[11];
    const float* cbb     = (const float*)d_in[12];
    const float* W_ih    = (const float*)d_in[13];
    const float* W_hh    = (const float*)d_in[14];
    const float* b_ih    = (const float*)d_in[15];
    const float* b_hh    = (const float*)d_in[16];
    const float* fco_w   = (const float*)d_in[17];
    const float* fco_b   = (const float*)d_in[18];
    float* pred = (float*)d_out;

    char* ws = (char*)d_ws;
    size_t off = 0;
    unsigned short* WaH   = (unsigned short*)(ws + off); off += (size_t)NG2 * KA * 2;  //   204,800
    unsigned short* WaF   = (unsigned short*)(ws + off); off += (size_t)NG2 * KA * 2;
    float4*         edges = (float4*)(ws + off);         off += (size_t)NN * NN * 16;  //   541,696
    int*            cnt   = (int*)(ws + off);            off += 16;
    unsigned short* phist = (unsigned short*)(ws + off); off += (size_t)BB * TH * NN * 2; // 2,260,992
    char*           xrec  = (char*)(ws + off);
    off += (size_t)BB * TF * REC_F;                                                    // 54,263,808

    hipMemsetAsync(cnt, 0, 16, stream);
    prep_weights<<<(NG2 * KA + 255) / 256, 256, 0, stream>>>(
        W_hh_h, W_ih_h, W_hh, W_ih, b_ih_h, b_hh_h, b_ih, b_hh, fch_w, fch_b,
        WaH, WaF);
    prep_edges<<<(NN * NN + 255) / 256, 256, 0, stream>>>(angles, adj, edges, cnt);
    prep_hist<<<(BB * TH * NN + 255) / 256, 256, 0, stream>>>(pm25, phist);
    prep_graph<<<BB * TF, 256, 0, stream>>>(
        feature, edges, cnt, cw0, cw1, cbb, xrec);

    fused_dgc<<<BB, NT, 0, stream>>>(
        WaH, WaF, fch_w, fch_b, fco_w, fco_b, cw0, cw1, xrec, phist, pred);
}